// Round 16
// baseline (512.764 us; speedup 1.0000x reference)
//
#include <hip/hip_runtime.h>
#include <hip/hip_bf16.h>

// Problem constants (from reference)
#define N_NODES 50000
#define N_EDGES 200000
#define BGRAPHS 512
#define F0c 78
#define H1c 10
#define HC1 780     // H1*F0 (logical)
#define HSTR 832    // padded row stride: 10 head blocks of 80 (78 data + 2 pad) + 32 K-pad cols
#define C2c 128
#define SEQc 1000
#define VOCABc 26
#define NFc 32
#define KWc 8
#define LOUTc 121
#define EMBc 128
#define KX 96       // padded cols for xpad (78 -> 96)
#define KXT 3872    // NF*LOUT = 32*121 -> 121 MFMA k-steps
#define MROWS 13312 // 512*26 one-hot rows = 104 * 128 exactly
#define KM 1024     // padded K for Amat GEMM (1000 -> 1024)
#define W2TF_N (25*8*64*8)   // w2t in MFMA-fragment order: [kstep 25][colgrp 8][lane 64][8 bf16]
#define NSCANB 196  // scan blocks: ceil(50000/256)

typedef __attribute__((ext_vector_type(8))) short short8;
typedef __attribute__((ext_vector_type(4))) float f32x4;
typedef unsigned short u16;

static constexpr size_t alignup(size_t x) { return (x + 255) & ~size_t(255); }

// -------- workspace layout (bytes) --------
// A_HBUF region: formerly xagg (now eliminated by fusion); aliases live here later.
static constexpr size_t A_HBUF = 0;
static constexpr size_t A_OUT1 = alignup(A_HBUF + size_t(N_NODES)*HSTR*2);   // (dead slot; xpad alias lives here)
static constexpr size_t A_H2   = alignup(A_OUT1 + size_t(N_NODES)*HSTR*2);   // f32  [N,128]
static constexpr size_t A_W2T  = alignup(A_H2   + size_t(N_NODES)*C2c*4);    // bf16 w2tf fragment layout (200 KB)
static constexpr size_t A_ALS1 = alignup(A_W2T  + size_t(C2c)*HSTR*2);
static constexpr size_t A_ALD1 = alignup(A_ALS1 + size_t(N_NODES)*H1c*4);
static constexpr size_t A_ALS2 = alignup(A_ALD1 + size_t(N_NODES)*H1c*4);
static constexpr size_t A_ALD2 = alignup(A_ALS2 + size_t(N_NODES)*4);
static constexpr size_t A_DEG  = alignup(A_ALD2 + size_t(N_NODES)*4);
static constexpr size_t A_OFFS = alignup(A_DEG  + size_t(N_NODES)*4);
static constexpr size_t A_CUR  = alignup(A_OFFS + size_t(N_NODES+1)*4);
static constexpr size_t A_CSRC = alignup(A_CUR  + size_t(N_NODES)*4);
static constexpr size_t A_XC   = alignup(A_CSRC + size_t(N_EDGES+N_NODES)*4);
static constexpr size_t A_Y1   = alignup(A_XC   + size_t(BGRAPHS)*256*4);
static constexpr size_t A_BOFF = alignup(A_Y1   + size_t(BGRAPHS)*1024*4);   // scan block-sums live here
static constexpr size_t A_BPAD = alignup(A_BOFF + size_t(BGRAPHS)*(VOCABc+1)*4);
static constexpr size_t A_WXT  = alignup(A_BPAD + size_t(HSTR)*4);           // bf16 [121][8][64][8] fragment order
static constexpr size_t A_FXP  = alignup(A_WXT  + size_t(C2c)*KXT*2);        // f32 [11][512][128]
static constexpr size_t A_W1HP = alignup(A_FXP  + size_t(11)*BGRAPHS*C2c*4); // bf16 [10][80][96]
static constexpr size_t A_WSD  = alignup(A_W1HP + size_t(10)*80*96*2);       // f32 [2][10][78]
static constexpr size_t A_CWT  = alignup(A_WSD  + size_t(2)*H1c*F0c*4);      // bf16 [2][256][1024] hi/lo conv_w^T
static constexpr size_t A_END  = alignup(A_CWT  + size_t(2)*256*KM*2);
static_assert(W2TF_N*2 <= size_t(C2c)*HSTR*2, "w2tf fits old slot");
static_assert((NSCANB+1)*4 <= BGRAPHS*(VOCABc+1)*4, "bsum fits A_BOFF slot");

// aliases inside the A_HBUF region (nothing writes it before these now):
static constexpr size_t A_HFIN = A_HBUF;                                        // f32 [N,128]
static constexpr size_t A_AMAT = alignup(A_HFIN + size_t(N_NODES)*C2c*4);       // f32 [13312][256]
static constexpr size_t A_CVO  = alignup(A_AMAT + size_t(MROWS)*256*4);         // bf16 [512][3872]
static constexpr size_t A_M    = alignup(A_CVO  + size_t(BGRAPHS)*KXT*2);       // bf16 [13312][1024] one-hot
static_assert(A_M + size_t(MROWS)*KM*2 <= size_t(N_NODES)*HSTR*2, "alias A overflow");
// alias inside out1 region (xpad is read by k_fuse012; slot otherwise unused):
static constexpr size_t A_XPAD = A_OUT1;                                        // bf16 [N,96]
static_assert(size_t(N_NODES)*KX*2 <= size_t(N_NODES)*HSTR*2, "alias B overflow");

// -------- helpers --------
__device__ __forceinline__ float bflo(unsigned u) { return __uint_as_float(u << 16); }
__device__ __forceinline__ float bfhi(unsigned u) { return __uint_as_float(u & 0xffff0000u); }
__device__ __forceinline__ u16 f2bf(float v) {
    __hip_bfloat16 b = __float2bfloat16(v);
    return *(u16*)&b;
}
// wave-local ordering fence (validated on HW in R14: absmax-clean for wave-private LDS)
#define WSYNC() __builtin_amdgcn_wave_barrier()

// async global->LDS, 16B per lane; LDS dest = wave-uniform base + lane*16
#define GLOAD16(g, l) __builtin_amdgcn_global_load_lds( \
    (const __attribute__((address_space(1))) void*)(g), \
    (__attribute__((address_space(3))) void*)(l), 16, 0, 0)

// ---------------- prep: deg init + conversions + folded attention vectors ----------------
__global__ void k_prep(const float* __restrict__ x, const float* __restrict__ W1,
                       const float* __restrict__ W2, const float* __restrict__ b1,
                       const float* __restrict__ fcxt_w, const float* __restrict__ conv_w,
                       const float* __restrict__ a_src1, const float* __restrict__ a_dst1,
                       __hip_bfloat16* __restrict__ xpad, __hip_bfloat16* __restrict__ w1hp,
                       u16* __restrict__ w2tf, float* __restrict__ bpad,
                       u16* __restrict__ wxt, float* __restrict__ wsd,
                       u16* __restrict__ cwt, int* __restrict__ deg) {
    int i = blockIdx.x*256 + threadIdx.x;
    const int R0 = N_NODES;
    const int R1 = R0 + N_NODES*KX;
    const int R2 = R1 + 10*80*96;
    const int R3 = R2 + W2TF_N;
    const int R4 = R3 + HSTR;
    const int R5 = R4 + C2c*KXT;
    const int R6 = R5 + 2*H1c*F0c;
    const int R7 = R6 + 256*KM;
    if (i < R0) {
        deg[i] = 1;   // self loop
    } else if (i < R1) {
        int t = i - R0; int n = t / KX, c = t - n*KX;
        xpad[t] = __float2bfloat16(c < F0c ? x[(size_t)n*F0c + c] : 0.f);
    } else if (i < R2) {
        int t = i - R1; int hh = t / 7680, rem = t - hh*7680;
        int j = rem / 96, k = rem - j*96;
        w1hp[t] = __float2bfloat16((j < F0c && k < F0c) ? W1[(size_t)k*HC1 + hh*F0c + j] : 0.f);
    } else if (i < R3) {
        // w2t in MFMA fragment order: frag index -> (kstep, colgrp, quad, m16), elem t in 0..7
        int t = i - R2; int frag = t >> 3, tt = t & 7;
        int m16 = frag & 15, quad = (frag >> 4) & 3, cbg = (frag >> 6) & 7, kstep = frag >> 9;
        int col = cbg*16 + m16;
        int k = kstep*32 + quad*8 + tt;
        int hh = k / 80, cc = k - hh*80;
        w2tf[t] = f2bf((cc < F0c) ? W2[(size_t)(hh*F0c + cc)*C2c + col] : 0.f);
    } else if (i < R4) {
        int p = i - R3; int hh = p / 80, cc = p - hh*80;
        bpad[p] = (hh < H1c && cc < F0c) ? b1[hh*F0c + cc] : 0.f;
    } else if (i < R5) {
        // fc_xt weights in MFMA fragment order: [kt 121][ct 8][lane 64][8 bf16]
        int t = i - R4; int frag = t >> 3, tt = t & 7;
        int lane = frag & 63, m16 = lane & 15, quad = lane >> 4;
        int ct = (frag >> 6) & 7, kt = frag >> 9;
        wxt[t] = f2bf(fcxt_w[(size_t)(kt*32 + quad*8 + tt)*C2c + (ct*16 + m16)]);
    } else if (i < R6) {
        int t = i - R5; int sd = t / (H1c*F0c), rem = t - sd*(H1c*F0c);
        int hh = rem / F0c, c = rem - hh*F0c;
        const float* a = sd ? a_dst1 : a_src1;
        float v = 0.f;
        for (int j = 0; j < F0c; j++) v += W1[(size_t)c*HC1 + hh*F0c + j] * a[hh*F0c + j];
        wsd[t] = v;
    } else if (i < R7) {
        // conv_w^T hi/lo split: cwt[0][col][i] = bf16(v), cwt[1][col][i] = bf16(v - f32(hi))
        int t = i - R6; int col = t >> 10, ii = t & (KM-1);
        int o = col >> 3, k = col & 7;
        float v = (ii < SEQc) ? conv_w[((size_t)o*SEQc + ii)*KWc + k] : 0.f;
        u16 h = f2bf(v);
        float hv = __uint_as_float((unsigned)h << 16);
        cwt[(size_t)col*KM + ii] = h;
        cwt[(size_t)256*KM + (size_t)col*KM + ii] = f2bf(v - hv);
    }
}
#define PREP_TOTAL (N_NODES + N_NODES*KX + 10*80*96 + W2TF_N + HSTR + C2c*KXT + 2*H1c*F0c + 256*KM)

// ---------------- CSR build ----------------
__global__ void k_count(const int* __restrict__ ei, int* deg) {
    int i = blockIdx.x*256 + threadIdx.x;
    if (i < N_EDGES) atomicAdd(&deg[ei[N_EDGES + i]], 1);
}
// Multi-block exclusive scan (R13: replaced single-block scan, -37us). Integer-exact.
__global__ void k_scan1(const int* __restrict__ deg, int* __restrict__ offs,
                        int* __restrict__ bsum, int n) {
    int b = blockIdx.x, tid = threadIdx.x, lane = tid & 63, wid = tid >> 6;
    int i = b*256 + tid;
    int v0 = (i < n) ? deg[i] : 0;
    int v = v0;
    for (int d = 1; d < 64; d <<= 1) { int t = __shfl_up(v, d, 64); if (lane >= d) v += t; }
    __shared__ int ws[4];
    if (lane == 63) ws[wid] = v;
    __syncthreads();
    if (tid == 0) {
        int r = 0;
        #pragma unroll
        for (int w = 0; w < 4; w++) { int t = ws[w]; ws[w] = r; r += t; }
        bsum[b] = r;
    }
    __syncthreads();
    if (i < n) offs[i] = ws[wid] + (v - v0);   // exclusive local prefix
}
__global__ void k_scan2(int* __restrict__ bsum, int nb) {
    __shared__ int s[NSCANB];
    int tid = threadIdx.x;
    for (int i = tid; i < nb; i += 256) s[i] = bsum[i];
    __syncthreads();
    if (tid == 0) {
        int r = 0;
        for (int b = 0; b < nb; b++) { int t = s[b]; s[b] = r; r += t; }
        bsum[nb] = r;                           // total
    }
    __syncthreads();
    for (int i = tid; i < nb; i += 256) bsum[i] = s[i];
}
__global__ void k_scan3(const int* __restrict__ bsum, int* __restrict__ offs,
                        int* __restrict__ cur, int n, int nb) {
    int b = blockIdx.x, i = b*256 + threadIdx.x;
    if (i < n) {
        int o = offs[i] + bsum[b];
        offs[i] = o; cur[i] = o;
    } else if (i == n) {
        offs[n] = bsum[nb];
    }
}
__global__ void k_fill(const int* __restrict__ ei, int* cur, int* __restrict__ csrc) {
    int i = blockIdx.x*256 + threadIdx.x;
    if (i < N_EDGES) {
        int s = ei[i], d = ei[N_EDGES + i];
        int p = atomicAdd(&cur[d], 1);
        csrc[p] = s;
    } else if (i < N_EDGES + N_NODES) {
        int n = i - N_EDGES;
        int p = atomicAdd(&cur[n], 1);
        csrc[p] = n;
    }
}
// determinize: sort each CSR segment (atomic fill order varies run-to-run)
__global__ void k_sortcsr(const int* __restrict__ offs, int* __restrict__ csrc) {
    int n = blockIdx.x*256 + threadIdx.x;
    if (n >= N_NODES) return;
    int s = offs[n], e = offs[n+1];
    for (int i = s + 1; i < e; i++) {
        int v = csrc[i];
        int j = i - 1;
        while (j >= s && csrc[j] > v) { csrc[j+1] = csrc[j]; j--; }
        csrc[j+1] = v;
    }
}

// ---------------- layer-1 attention logits, direct from x: als = x @ (W1_h a_h) ----------------
__global__ void k_att1x(const float* __restrict__ x, const float* __restrict__ wsd,
                        float* __restrict__ als, float* __restrict__ ald) {
    int i = blockIdx.x*256 + threadIdx.x;
    if (i >= N_NODES*H1c) return;
    int n = i / H1c, hh = i - n*H1c;
    const float* xr = x + (size_t)n*F0c;
    const float* ws = wsd + hh*F0c;
    const float* wd = wsd + H1c*F0c + hh*F0c;
    float s1 = 0.f, s2 = 0.f;
    for (int c = 0; c < F0c; c++) { float v = xr[c]; s1 += v*ws[c]; s2 += v*wd[c]; }
    als[i] = s1; ald[i] = s2;
}

// ---------------- FUSED agg1 + gemm1(ELU) + gemm2 + att2 fold ----------------
// Eliminates the 80 MB xagg intermediate (agg1x wrote it, fuse12 re-read it; measured
// FETCH showed ~40 MB of it missing L3 to HBM). Per 16-row block:
//  phase 0: each wave aggregates 4 nodes (R14's validated barrier-free wave-local scheme),
//           writing bf16 pairs into LDS tile Xs with the SAME swizzled layout as As.
//           Overread block (bytes 1536..1663/row) zeroed so kt=2/quad>=2 fragment reads
//           see exact zeros (x B-zero = 0, matching old finite-x-zero behavior).
//  phase 1: per-head 80x80 GEMM reads A-fragments from Xs (identical values as the old
//           global xagg reads -> bit-identical As), writes ELU'd As.
//  phase 2 + epilogue: unchanged from the proven fuse12 v5.
// LDS: Xs 26,624 + As 26,624 (phase-0 scratch overlaid on As) = 53.25 KB -> 3 blocks/CU.
// launch_bounds(256,4): VGPR cap 128 >> live ~70 (R5/R8 spill rule).
__global__ void __launch_bounds__(256, 4)
k_fuse012(const unsigned* __restrict__ xpu, const float* __restrict__ als,
          const float* __restrict__ ald, const int* __restrict__ offs,
          const int* __restrict__ csrc,
          const short* __restrict__ w1hp, const float* __restrict__ bpad,
          const short* __restrict__ w2tf,
          const float* __restrict__ a_src2, const float* __restrict__ a_dst2,
          float* __restrict__ Cout, float* __restrict__ als2, float* __restrict__ ald2) {
    constexpr int H = H1c;
    __shared__ __attribute__((aligned(16))) short Xs[16*832];      // 26,624 B agg staging
    __shared__ __attribute__((aligned(16))) short As[16*832];      // 26,624 B phase-1 out
    int tid = threadIdx.x;
    int wave = tid >> 6, lane = tid & 63;                          // 4 waves
    int m16 = lane & 15, quad = lane >> 4;
    int blockrow = blockIdx.x * 16;                                // 3125*16 = 50000 exact

    // phase-0 per-wave scratch overlaid on As (dead until phase 1 writes it)
    float* wexp   = (float*)As + wave*(64*H);                      // 4 x 2560 B
    int*   ssrc   = (int*)((char*)As + 10240) + wave*64;           // 4 x 256 B
    float* ms     = (float*)((char*)As + 11264) + wave*H;          // 4 x 40 B
    float* dinv_s = (float*)((char*)As + 11424) + wave*H;          // 4 x 40 B

    // ---- phase 0: aggregation, 4 nodes per wave, results -> Xs (swizzled bf16 pairs) ----
    for (int rr = 0; rr < 4; rr++) {
        int rl = wave*4 + rr;
        int dn = blockrow + rl;
        int s = offs[dn], e = offs[dn+1], deg = e - s;
        char* xrow = (char*)Xs + rl*1664;
        int swz = (rl & 7) << 4;
        // zero the last 128B block of the row: swizzle images of overread slots must be 0
        if (lane < 32) *(unsigned*)(xrow + 1536 + lane*4) = 0u;
        if (deg <= 64) {
            if (lane < deg) ssrc[lane] = csrc[s + lane];
            WSYNC();
            for (int idx = lane; idx < deg*H; idx += 64) {
                int j = idx / H, hh = idx - j*H;
                float al = als[(size_t)ssrc[j]*H + hh] + ald[(size_t)dn*H + hh];
                wexp[idx] = (al >= 0.f) ? al : 0.2f*al;
            }
            WSYNC();
            if (lane < H) {
                float m = -1e30f;
                for (int j = 0; j < deg; j++) m = fmaxf(m, wexp[j*H + lane]);
                float den = 0.f;
                for (int j = 0; j < deg; j++) den += __expf(wexp[j*H + lane] - m);
                ms[lane] = m; dinv_s[lane] = 1.f/(den + 1e-16f);
            }
            WSYNC();
            for (int idx = lane; idx < deg*H; idx += 64) {
                int hh = idx % H;
                wexp[idx] = __expf(wexp[idx] - ms[hh]) * dinv_s[hh];
            }
            WSYNC();
            if (lane < 40) {                   // u32 covers cols 2*lane, 2*lane+1 per head
                float accL[H], accH[H];
                #pragma unroll
                for (int hh = 0; hh < H; hh++) { accL[hh] = 0.f; accH[hh] = 0.f; }
                int j = 0;
                for (; j + 1 < deg; j += 2) {
                    unsigned ua = xpu[(size_t)ssrc[j]*48 + lane];
                    unsigned ub = xpu[(size_t)ssrc[j+1]*48 + lane];
                    float a0 = bflo(ua), a1 = bfhi(ua), b0 = bflo(ub), b1 = bfhi(ub);
                    #pragma unroll
                    for (int hh = 0; hh < H; hh++) {
                        float wA = wexp[j*H + hh], wB = wexp[(j+1)*H + hh];
                        accL[hh] += wA*a0 + wB*b0;
                        accH[hh] += wA*a1 + wB*b1;
                    }
                }
                if (j < deg) {
                    unsigned ua = xpu[(size_t)ssrc[j]*48 + lane];
                    float a0 = bflo(ua), a1 = bfhi(ua);
                    #pragma unroll
                    for (int hh = 0; hh < H; hh++) {
                        float wA = wexp[j*H + hh];
                        accL[hh] += wA*a0;
                        accH[hh] += wA*a1;
                    }
                }
                #pragma unroll
                for (int hh = 0; hh < H; hh++) {
                    unsigned p = (unsigned)f2bf(accL[hh]) | ((unsigned)f2bf(accH[hh]) << 16);
                    *(unsigned*)(xrow + ((hh*160 + lane*4) ^ swz)) = p;
                }
            }
            WSYNC();
        } else {
            // fallback deg>64 (practically never): recompute alpha inline, same math
            if (lane < H) {
                float adv = ald[(size_t)dn*H + lane];
                float m = -1e30f;
                for (int j = s; j < e; j++) {
                    float al = als[(size_t)csrc[j]*H + lane] + adv;
                    al = (al >= 0.f) ? al : 0.2f*al;
                    m = fmaxf(m, al);
                }
                float den = 0.f;
                for (int j = s; j < e; j++) {
                    float al = als[(size_t)csrc[j]*H + lane] + adv;
                    al = (al >= 0.f) ? al : 0.2f*al;
                    den += __expf(al - m);
                }
                ms[lane] = m; dinv_s[lane] = 1.f/(den + 1e-16f);
            }
            WSYNC();
            if (lane < 40) {
                float accL[H], accH[H];
                #pragma unroll
                for (int hh = 0; hh < H; hh++) { accL[hh] = 0.f; accH[hh] = 0.f; }
                for (int j = s; j < e; j++) {
                    int sj = csrc[j];
                    unsigned ua = xpu[(size_t)sj*48 + lane];
                    float a0 = bflo(ua), a1 = bfhi(ua);
                    #pragma unroll
                    for (int hh = 0; hh < H; hh++) {
                        float al = als[(size_t)sj*H + hh] + ald[(size_t)dn*H + hh];
                        al = (al >= 0.f) ? al : 0.2f*al;
                        float a = __expf(al - ms[hh]) * dinv_s[hh];
                        accL[hh] += a*a0;
                        accH[hh] += a*a1;
                    }
                }
                #pragma unroll
                for (int hh = 0; hh < H; hh++) {
                    unsigned p = (unsigned)f2bf(accL[hh]) | ((unsigned)f2bf(accH[hh]) << 16);
                    *(unsigned*)(xrow + ((hh*160 + lane*4) ^ swz)) = p;
                }
            }
            WSYNC();
        }
    }
    __syncthreads();   // Xs complete for all 16 rows; As scratch dead

    // ---- phase 1: per-head 80x80 GEMM + bias + ELU, A from Xs -> As (swizzled bf16) ----
    {
        int hg = wave;                           // heads {hg, hg+4, hg+8 if hg<2}
        int S1 = (m16 & 7) << 4;
        const char* xrowR = (const char*)Xs + m16*1664;
        for (int hh = hg; hh < H1c; hh += 4) {
            f32x4 acc1[5];
            #pragma unroll
            for (int ct = 0; ct < 5; ct++) acc1[ct] = (f32x4){0.f,0.f,0.f,0.f};
            #pragma unroll
            for (int kt = 0; kt < 3; kt++) {
                // kt=2,quad>=2 overreads: Xs slots zeroed, B zeros neutralize (exact 0)
                short8 af = *(const short8*)(xrowR + ((hh*160 + (kt*4 + quad)*16) ^ S1));
                #pragma unroll
                for (int ct = 0; ct < 5; ct++) {
                    const short8* brow = (const short8*)(w1hp + (size_t)(hh*80 + ct*16 + m16)*96);
                    acc1[ct] = __builtin_amdgcn_mfma_f32_16x16x32_bf16(af, brow[kt*4 + quad],
                                                                      acc1[ct], 0, 0, 0);
                }
            }
            #pragma unroll
            for (int ct = 0; ct < 5; ct++) {
                int col = hh*80 + ct*16 + m16;
                float bv = bpad[col];
                #pragma unroll
                for (int r = 0; r < 4; r++) {
                    int rl = quad*4 + r;
                    float v = acc1[ct][r] + bv;
                    v = (v > 0.f) ? v : (__expf(v) - 1.f);
                    *(u16*)((char*)As + rl*1664 + ((col*2) ^ ((rl & 7) << 4))) = f2bf(v);
                }
            }
        }
    }
    __syncthreads();   // As complete

    // ---- phase 2: gemm2, A from LDS, B direct from global fragment layout; no barriers ----
    int cg = wave;                               // 4 col-groups of 32
    f32x4 acc[2];
    acc[0] = (f32x4){0.f,0.f,0.f,0.f};
    acc[1] = (f32x4){0.f,0.f,0.f,0.f};
    int S = (m16 & 7) << 4;                      // read-side swizzle (row&7 == m16&7)
    const char* asRow = (const char*)As + (size_t)m16*1664;
    const short8* bp = (const short8*)w2tf;
    #pragma unroll 5
    for (int kstep = 0; kstep < 25; kstep++) {
        short8 af = *(const short8*)(asRow + ((kstep*64 + quad*16) ^ S));
        short8 b0 = bp[(size_t)(kstep*8 + cg*2    )*64 + lane];
        short8 b1 = bp[(size_t)(kstep*8 + cg*2 + 1)*64 + lane];
        acc[0] = __builtin_amdgcn_mfma_f32_16x16x32_bf16(af, b0, acc[0], 0, 0, 0);
        acc[1] = __builtin_amdgcn_mfma_f32_16x16x32_bf16(af, b1, acc[1], 0, 0, 0);
    }

    // ---- epilogue: C-write (global; does not touch As) ----
    float asv[2], adv[2];
    #pragma unroll
    for (int ct = 0; ct < 2; ct++) {
        asv[ct] = a_src2[cg*32 + ct*16 + m16];
        adv[ct] = a_dst2[cg*32 + ct*16 + m16];
    }
    #pragma unroll
    for (int ct = 0; ct < 2; ct++) {
        int col = cg*32 + ct*16 + m16;
        #pragma unroll
        for (int r = 0; r < 4; r++) {
            int orow = blockrow + quad*4 + r;
            Cout[(size_t)orow*C2c + col] = acc[ct][r];
        }
    }

    // ---- att2 fold: partials overlaid on As (dead after phase 2) ----
    __syncthreads();                             // all As reads complete before reuse
    float* sred  = (float*)As;                   // [16][4]
    float* sredd = sred + 64;                    // [16][4]
    #pragma unroll
    for (int r = 0; r < 4; r++) {
        float s1 = 0.f, s2 = 0.f;
        #pragma unroll
        for (int ct = 0; ct < 2; ct++) { s1 += acc[ct][r]*asv[ct]; s2 += acc[ct][r]*adv[ct]; }
        #pragma unroll
        for (int d = 1; d < 16; d <<= 1) { s1 += __shfl_xor(s1, d, 64); s2 += __shfl_xor(s2, d, 64); }
        if (m16 == 0) {
            int rl = quad*4 + r;
            sred[rl*4 + cg] = s1;
            sredd[rl*4 + cg] = s2;
        }
    }
    __syncthreads();
    if (tid < 16) {
        int orow = blockrow + tid;
        als2[orow] = sred[tid*4+0] + sred[tid*4+1] + sred[tid*4+2] + sred[tid*4+3];
        ald2[orow] = sredd[tid*4+0] + sredd[tid*4+1] + sredd[tid*4+2] + sredd[tid*4+3];
    }
}

// ---------------- GAT layer-2 aggregation (H=1, C=128 f32) ----------------
// FINAL (R13 config): 1-wave blocks; gather latency-bound (R10/R14 established).
__global__ void k_agg2(const float* __restrict__ h2, const float* __restrict__ als,
                       const float* __restrict__ ald, const int* __restrict__ offs,
                       const int* __restrict__ csrc, const float* __restrict__ b2,
                       float* __restrict__ out) {
    int dn = blockIdx.x, lane = threadIdx.x;   // 64
    int s = offs[dn], e = offs[dn+1], deg = e - s;
    __shared__ float wexp[128];
    __shared__ int ssrc[128];

    if (deg <= 128) {
        float adv = ald[dn];
        for (int j = lane; j < deg; j += 64) {
            int sj = csrc[s + j];
            ssrc[j] = sj;
            float al = als[sj] + adv;
            wexp[j] = (al >= 0.f) ? al : 0.2f*al;
        }
        __syncthreads();
        float m = -1e30f;
        for (int j = lane; j < deg; j += 64) m = fmaxf(m, wexp[j]);
        #pragma unroll
        for (int d = 32; d > 0; d >>= 1) m = fmaxf(m, __shfl_xor(m, d, 64));
        __syncthreads();
        float den = 0.f;
        for (int j = lane; j < deg; j += 64) {
            float ex = __expf(wexp[j] - m);
            wexp[j] = ex;
            den += ex;
        }
        #pragma unroll
        for (int d = 32; d > 0; d >>= 1) den += __shfl_xor(den, d, 64);
        float dinv = 1.f/(den + 1e-16f);
        __syncthreads();
        float2 acc = {0.f, 0.f};
        for (int j = 0; j < deg; j++) {
            float alpha = wexp[j] * dinv;
            float2 v = ((const float2*)(h2 + (size_t)ssrc[j]*C2c))[lane];
            acc.x += alpha*v.x; acc.y += alpha*v.y;
        }
        float2 o;
        o.x = fmaxf(acc.x + b2[2*lane], 0.f);
        o.y = fmaxf(acc.y + b2[2*lane+1], 0.f);
        ((float2*)(out + (size_t)dn*C2c))[lane] = o;
    } else {
        __shared__ float sm[2];
        if (lane == 0) {
            float adv = ald[dn];
            float m = -1e30f;
            for (int j = s; j < e; j++) {
                float al = als[csrc[j]] + adv;
                al = (al >= 0.f) ? al : 0.2f*al;
                m = fmaxf(m, al);
            }
            float den = 0.f;
            for (int j = s; j < e; j++) {
                float al = als[csrc[j]] + adv;
                al = (al >= 0.f) ? al : 0.2f*al;
                den += __expf(al - m);
            }
            sm[0] = m; sm[1] = 1.f/(den + 1e-16f);
        }
        __syncthreads();
        float m = sm[0], dinv = sm[1], adv = ald[dn];
        float2 acc = {0.f, 0.f};
        for (int j = s; j < e; j++) {
            int sj = csrc[j];
            float al = als[sj] + adv;
            al = (al >= 0.f) ? al : 0.2f*al;
            float alpha = __expf(al - m) * dinv;
            float2 v = ((const float2*)(h2 + (size_t)sj*C2c))[lane];
            acc.x += alpha*v.x; acc.y += alpha*v.y;
        }
        float2 o;
        o.x = fmaxf(acc.x + b2[2*lane], 0.f);
        o.y = fmaxf(acc.y + b2[2*lane+1], 0.f);
        ((float2*)(out + (size_t)dn*C2c))[lane] = o;
    }
}

// ---------------- pool + fc_g1 merged (g stays in LDS) ----------------
__global__ void k_poolfcg(const float* __restrict__ hf, const int* __restrict__ batch,
                          const float* __restrict__ W, const float* __restrict__ bias,
                          float* __restrict__ xc) {
    int b = blockIdx.x, tid = threadIdx.x;    // 128
    __shared__ int se[2];
    __shared__ float gs[C2c];
    if (tid < 2) {
        int key = b + tid;
        int lo = 0, hi = N_NODES;
        while (lo < hi) { int mid = (lo+hi) >> 1; if (batch[mid] < key) lo = mid+1; else hi = mid; }
        se[tid] = lo;
    }
    __syncthreads();
    int s = se[0], e = se[1];
    float m = -1e30f;
    for (int n = s; n < e; n++) m = fmaxf(m, hf[(size_t)n*C2c + tid]);
    gs[tid] = m;
    __syncthreads();
    float acc = bias[tid];
    for (int k = 0; k < C2c; k++) acc += gs[k] * W[k*C2c + tid];
    xc[b*256 + tid] = fmaxf(acc, 0.f);
}

// ---------------- conv path ----------------
// build one-hot matrix M[(b*26+t)][i] = (target[b,i]==t), bf16, K padded to 1024.
__global__ void k_buildM(const int* __restrict__ target, u16* __restrict__ Mm) {
    int b = blockIdx.x, tid = threadIdx.x;    // 256
    short8 z = (short8){0,0,0,0,0,0,0,0};
    short8* base = (short8*)(Mm + (size_t)b*VOCABc*KM);
    for (int i = tid; i < VOCABc*KM/8; i += 256) base[i] = z;
    __syncthreads();
    for (int i = tid; i < SEQc; i += 256) {
        int t = target[(size_t)b*SEQc + i];
        Mm[((size_t)b*VOCABc + t)*KM + i] = (u16)0x3F80;   // bf16 1.0
    }
}

// Amat via MFMA: A2[13312][256] = M[13312][1024] @ cwt^T (hi) + M @ cwt^T (lo).
__global__ void __launch_bounds__(256, 1)
k_amat_mfma(const short* __restrict__ Mm, const short* __restrict__ cwt,
            float* __restrict__ A2) {
    __shared__ __attribute__((aligned(16))) short As[2][128*64];
    __shared__ __attribute__((aligned(16))) short Bh[2][128*64];
    __shared__ __attribute__((aligned(16))) short Bl[2][128*64];
    int tid = threadIdx.x;
    int wave = tid >> 6, lane = tid & 63;
    int m16 = lane & 15, quad = lane >> 4;
    int blockrow = blockIdx.x * 128;       // 104 row-tiles
    int colbase  = blockIdx.y * 128;       // 2 col-tiles

    size_t aoff[4], bo[4];
    #pragma unroll
    for (int i = 0; i < 4; i++) {
        int c = wave*256 + i*64 + lane;
        int row = c >> 3;
        int cb  = (c & 7) << 4;
        int srcb = cb ^ ((row & 7) << 4);
        aoff[i] = (size_t)(blockrow + row) * (KM*2) + srcb;
        bo[i]   = (size_t)(colbase  + row) * (KM*2) + srcb;
    }
    const char* hbase = (const char*)cwt;
    const char* lbase = (const char*)(cwt + (size_t)256*KM);

    f32x4 acc[2][8];
    #pragma unroll
    for (int wr = 0; wr < 2; wr++)
        #pragma unroll
        for (int ct = 0; ct < 8; ct++) acc[wr][ct] = (f32x4){0.f,0.f,0.f,0.f};

    #pragma unroll
    for (int i = 0; i < 4; i++) {
        GLOAD16((const char*)Mm + aoff[i], &As[0][(wave*256 + i*64)*8]);
        GLOAD16(hbase + bo[i],             &Bh[0][(wave*256 + i*64)*8]);
        GLOAD16(lbase + bo[i],             &Bl[0][(wave*256 + i*64)*8]);
    }
    __syncthreads();

    int cur = 0;
    int S = (m16 & 7) << 4;
    for (int s = 0; s < KM/64; s++) {
        if (s + 1 < KM/64) {
            size_t kb = (size_t)(s + 1) * 128;
            #pragma unroll
            for (int i = 0; i < 4; i++) {
                GLOAD16((const char*)Mm + aoff[i] + kb, &As[cur^1][(wave*256 + i*64)*8]);
                GLOAD16(hbase + bo[i] + kb,             &Bh[cur^1][(wave*256 + i*64)*8]);
                GLOAD16(lbase + bo[i] + kb,             &Bl[cur^1][(wave*256 + i*64)*8]);
            }
        }
        const char* asBase = (const char*)&As[cur][0];
        const char* bhBase = (const char*)&Bh[cur][0];
        const char* blBase = (const char*)&Bl[cur][0];
        #pragma unroll
        for (int kk = 0; kk < 2; kk++) {
            int kb2 = (kk*64 + quad*16) ^ S;
            short8 af[2];
            #pragma unroll
            for (int wr = 0; wr < 2; wr++) {
                int row = wave*32 + wr*16 + m16;
                af[wr] = *(const short8*)(asBase + row*128 + kb2);
            }
            #pragma unroll
            for (int ct = 0; ct < 8; ct++) {
                int col = ct*16 + m16;
                short8 bhv = *(const short8*)(bhBase + col*128 + kb2);
                short8 blv = *(const short8*)(blBase + col*128 + kb2);
                acc[0][ct] = __builtin_amdgcn_mfma_f32_16x16x32_bf16(af[0], bhv, acc[0][ct], 0, 0, 0);
                acc[1][ct] = __builtin_amdgcn_mfma_f32_16x16x32_bf16(af[1], bhv, acc[1][ct], 0, 0, 0);
                acc[0][ct] = __builtin_amdgcn_mfma_f32_16x16x32_bf16(af[0], blv, acc[0][ct], 0, 0, 0);
                acc[1][ct] = __builtin_amdgcn_mfma_f32_16x16x32_bf16(af[1], blv, acc[1][ct], 0, 0, 0);
            }
        }
        __syncthreads();
        cur ^= 1;
    }

    #pragma unroll
    for (int wr = 0; wr < 2; wr++) {
        int rowbase = blockrow + wave*32 + wr*16 + quad*4;
        #pragma unroll
        for (int ct = 0; ct < 8; ct++) {
            int col = colbase + ct*16 + m16;
            #pragma unroll
            for (int r = 0; r < 4; r++) {
                A2[(size_t)(rowbase + r)*256 + col] = acc[wr][ct][r];
            }
        }
    }
}

__global__ void __launch_bounds__(128, 4)
k_conv(const float* __restrict__ A2, const float* __restrict__ emb,
       const float* __restrict__ convb, u16* __restrict__ convout) {
    int b = blockIdx.x, og = blockIdx.y;      // og in 0..7 -> o base og*4
    int tid = threadIdx.x;                    // 128
    __shared__ float embs[VOCABc*EMBc];       // 13.3 KB
    __shared__ float arow[4*VOCABc*KWc];      // 3.3 KB
    for (int i = tid; i < VOCABc*EMBc; i += 128) embs[i] = emb[i];
    for (int i = tid; i < 4*VOCABc*KWc; i += 128) {
        int o2 = i / (VOCABc*KWc);
        int rem = i - o2*(VOCABc*KWc);        // t*8+k
        int t = rem >> 3, k = rem & 7;
        arow[i] = A2[((size_t)b*VOCABc + t)*256 + (og*4 + o2)*8 + k];
    }
    __syncthreads();
    if (tid < LOUTc) {
        float a0 = convb[og*4+0], a1 = convb[og*4+1], a2 = convb[og*4+2], a3 = convb[og*4+3];
        for (int t = 0; t < VOCABc; t++) {
            #pragma unroll
            for (int k = 0; k < KWc; k++) {
                float ev = embs[t*EMBc + tid + k];
                a0 += arow[0*(VOCABc*KWc) + t*KWc + k] * ev;
                a1 += arow[1*(VOCABc*KWc) + t*KWc + k] * ev;
                a2 += arow[2*(VOCABc*KWc) + t*KWc + k] * ev;
                a3 += arow[3*(VOCABc*KWc) + t*KWc + k] * ev;
            }
        }
        size_t base = (size_t)b*KXT + (og*4)*LOUTc + tid;
        convout[base            ] = f2bf(fmaxf(a0, 0.f));
        convout[base +   LOUTc  ] = f2bf(fmaxf(a1, 0.f));
        convout[base + 2*LOUTc  ] = f2bf(fmaxf(a2, 0.f));
        convout[base + 3*LOUTc  ] = f2bf(fmaxf(a3, 0.f));
    }
}
// fc_xt partials via MFMA; B (wxt) in fragment order -> fully coalesced 16B/lane loads.
__global__ void k_fcxt_mfma(const short* __restrict__ cvo, const short* __restrict__ wxt,
                            float* __restrict__ fxp) {
    int wave = threadIdx.x >> 6, lane = threadIdx.x & 63;
    int m16 = lane & 15, quad = lane >> 4;
    int r0 = blockIdx.x*64 + wave*16;      // 512 rows = 8 blocks * 64
    int kt0 = blockIdx.y*11;               // 121 k-steps = 11 chunks * 11
    const short8* arow = (const short8*)(cvo + (size_t)(r0 + m16)*KXT);
    const short8* bp = (const short8*)wxt;
    f32x4 acc[8];
    #pragma unroll
    for (int ct = 0; ct < 8; ct++) acc[ct] = (f32x4){0.f,0.f,0.f,0.f};
    for (int kt = kt0; kt < kt0 + 11; kt++) {
        short8 af = arow[kt*4 + quad];
        #pragma unroll
        for (int ct = 0; ct < 8; ct++) {
            short8 bf = bp[(size_t)(kt*8 + ct)*64 + lane];
            acc[ct] = __builtin_amdgcn_mfma_f32_16x16x32_bf16(af, bf, acc[ct], 0, 0, 0);
        }
    }
    #pragma unroll
    for (int ct = 0; ct < 8; ct++) {
        int col = ct*16 + m16;
        #pragma unroll
        for (int r = 0; r < 4; r++) {
            int row = r0 + quad*4 + r;
            fxp[((size_t)blockIdx.y*BGRAPHS + row)*C2c + col] = acc[ct][r];
        }
    }
}

// ---------------- head MLP ----------------
// fc1 v2: 8 graphs per block x 4 col-quarters. W traffic 512 MB -> 64 MB. Bit-identical y1.
__global__ void __launch_bounds__(256, 4)
k_fc1(const float* __restrict__ xc, const float* __restrict__ fxp,
      const float* __restrict__ fcxt_b, const float* __restrict__ W,
      const float* __restrict__ bias, float* __restrict__ y1) {
    int g0 = blockIdx.x * 8;                  // 64 graph-groups
    int colq = blockIdx.y;                    // 4 col-quarters
    int tid = threadIdx.x;                    // 256
    __shared__ float xs[8][256];              // 8 KB
    for (int idx = tid; idx < 8*256; idx += 256) {
        int g = idx >> 8, k = idx & 255;
        int b = g0 + g;
        float v;
        if (k < 128) {
            v = xc[b*256 + k];
        } else {
            int col = k - 128;
            float s = fcxt_b[col];
            #pragma unroll
            for (int q = 0; q < 11; q++) s += fxp[((size_t)q*BGRAPHS + b)*C2c + col];
            v = s;
        }
        xs[g][k] = v;
    }
    __syncthreads();
    int col = colq*256 + tid;
    float a[8];
    #pragma unroll
    for (int g = 0; g < 8; g++) a[g] = bias[col];
    for (int k = 0; k < 256; k++) {
        float w = W[(size_t)k*1024 + col];    // coalesced; xs[g][k] is LDS broadcast
        #pragma unroll
        for (int g = 0; g < 8; g++) a[g] += xs[g][k] * w;
    }
    #pragma unroll
    for (int g = 0; g < 8; g++)
        y1[(size_t)(g0+g)*1024 + col] = fmaxf(a[g], 0.f);
}
// fc2out v2: 2 graphs per block. Bit-identical out.
__global__ void __launch_bounds__(256, 4)
k_fc2out(const float* __restrict__ y1, const float* __restrict__ W,
         const float* __restrict__ bias, const float* __restrict__ ow,
         const float* __restrict__ ob, float* __restrict__ out) {
    int g0 = blockIdx.x * 2;                  // 256 graph-groups
    int tid = threadIdx.x;                    // 256
    int lane = tid & 63, wid = tid >> 6;
    __shared__ float ys[2][1024];             // 8 KB
    __shared__ float wsum[2][4];
    for (int i = tid; i < 2048; i += 256)
        ys[i >> 10][i & 1023] = y1[(size_t)(g0 + (i >> 10))*1024 + (i & 1023)];
    __syncthreads();
    float acc0 = bias[tid], acc1 = bias[tid];
    for (int k = 0; k < 1024; k++) {
        float w = W[(size_t)k*256 + tid];     // coalesced; ys[g][k] is LDS broadcast
        acc0 += ys[0][k] * w;
        acc1 += ys[1][k] * w;
    }
    float v0 = fmaxf(acc0, 0.f) * ow[tid];
    float v1 = fmaxf(acc1, 0.f) * ow[tid];
    #pragma unroll
    for (int d = 32; d > 0; d >>= 1) { v0 += __shfl_xor(v0, d, 64); v1 += __shfl_xor(v1, d, 64); }
    if (lane == 0) { wsum[0][wid] = v0; wsum[1][wid] = v1; }
    __syncthreads();
    if (tid < 2)
        out[g0 + tid] = wsum[tid][0] + wsum[tid][1] + wsum[tid][2] + wsum[tid][3] + ob[0];
}

extern "C" void kernel_launch(void* const* d_in, const int* in_sizes, int n_in,
                              void* d_out, int out_size, void* d_ws, size_t ws_size,
                              hipStream_t stream) {
    (void)in_sizes; (void)n_in; (void)out_size;
    if (ws_size < A_END) return;   // guard: clean numeric-fail if ws too small

    const float* x       = (const float*)d_in[0];
    const int*   ei      = (const int*)  d_in[1];
    const int*   batch   = (const int*)  d_in[2];
    const int*   target  = (const int*)  d_in[3];
    const float* W1      = (const float*)d_in[4];
    const float* a_src1  = (const float*)d_in[5];
    const float* a_dst1  = (const float*)d_in[6];
    const float* b1      = (const float*)d_in[7];
    const float* W2      = (const float*)d_in[8];
    const float* a_src2  = (const float*)d_in[9];
    const float* a_dst2  = (const float*)d_in[10];
    const float* b2      = (const float*)d_in[11];
    const float* fcg_w   = (const float*)d_in[12];
    const float* fcg_b   = (const float*)d_in[13];
    const float* emb     = (const float*)d_in[14];
    const float* conv_w  = (const float*)d_in[15];
    const float* conv_b  = (const float*)d_in[16];
    const float* fcxt_w  = (const float*)d_in[17];
    const float* fcxt_b  = (const float*)d_in[18];
    const float* fc1_w   = (const float*)d_in[19];
    const float* fc1_b   = (const float*)d_in[20];
    const float* fc2_w   = (const float*)d_in[21];
    const float* fc2_b   = (const float*)d_in[22];
    const float* out_w   = (const float*)d_in[23];
    const float* out_b   = (const float*)d_in[24];

    char* wsb = (char*)d_ws;
    float* h2    = (float*)(wsb + A_H2);
    u16*   w2tf  = (u16*)  (wsb + A_W2T);
    float* als1  = (float*)(wsb + A_ALS1);
    float* ald1  = (float*)(wsb + A_ALD1);
    float* als2  = (float*)(wsb + A_ALS2);
    float* ald2  = (float*)(wsb + A_ALD2);
    int*   deg   = (int*)  (wsb + A_DEG);
    int*   offs  = (int*)  (wsb + A_OFFS);
    int*   cur   = (int*)  (wsb + A_CUR);
    int*   csrc  = (int*)  (wsb + A_CSRC);
    float* xc    = (float*)(wsb + A_XC);
    float* y1    = (float*)(wsb + A_Y1);
    int*   bsum  = (int*)  (wsb + A_BOFF);
    float* bpad  = (float*)(wsb + A_BPAD);
    u16*   wxt   = (u16*)  (wsb + A_WXT);
    float* fxp   = (float*)(wsb + A_FXP);
    __hip_bfloat16* w1hp = (__hip_bfloat16*)(wsb + A_W1HP);
    float* wsd   = (float*)(wsb + A_WSD);
    u16*   cwt   = (u16*)  (wsb + A_CWT);
    // aliases:
    float* hfin  = (float*)(wsb + A_HFIN);
    float* Amat2 = (float*)(wsb + A_AMAT);
    u16*   cvo   = (u16*)  (wsb + A_CVO);
    u16*   Mm    = (u16*)  (wsb + A_M);
    __hip_bfloat16* xpad = (__hip_bfloat16*)(wsb + A_XPAD);

    // prep
    k_prep<<<(PREP_TOTAL+255)/256, 256, 0, stream>>>(x, W1, W2, b1, fcxt_w, conv_w,
                                                     a_src1, a_dst1,
                                                     xpad, w1hp, w2tf, bpad, wxt, wsd, cwt, deg);
    // CSR build: count -> 3-kernel multi-block scan -> fill -> deterministic sort
    k_count  <<<(N_EDGES+255)/256, 256, 0, stream>>>(ei, deg);
    k_scan1  <<<NSCANB, 256, 0, stream>>>(deg, offs, bsum, N_NODES);
    k_scan2  <<<1, 256, 0, stream>>>(bsum, NSCANB);
    k_scan3  <<<NSCANB, 256, 0, stream>>>(bsum, offs, cur, N_NODES, NSCANB);
    k_fill   <<<(N_EDGES+N_NODES+255)/256, 256, 0, stream>>>(ei, cur, csrc);
    k_sortcsr<<<(N_NODES+255)/256, 256, 0, stream>>>(offs, csrc);

    // GAT layer 1 attention logits
    k_att1x<<<(N_NODES*H1c+255)/256, 256, 0, stream>>>(x, wsd, als1, ald1);

    // FUSED agg1 + gemm1(ELU) + gemm2 + att2 fold (xagg intermediate eliminated)
    k_fuse012<<<N_NODES/16, 256, 0, stream>>>((const unsigned*)xpad, als1, ald1, offs, csrc,
                                              (const short*)w1hp, bpad, (const short*)w2tf,
                                              a_src2, a_dst2, h2, als2, ald2);

    // one-hot matrix build (alias region; nothing writes A_HBUF before this now)
    k_buildM<<<BGRAPHS, 256, 0, stream>>>(target, Mm);

    k_agg2<<<N_NODES, 64, 0, stream>>>(h2, als2, ald2, offs, csrc, b2, hfin);

    // pool + fc_g1 -> xc[:, 0:128]
    k_poolfcg<<<BGRAPHS, 128, 0, stream>>>(hfin, batch, fcg_w, fcg_b, xc);

    // conv path: Amat = M @ conv_w^T (hi+lo), then conv + fc_xt partials
    k_amat_mfma<<<dim3(MROWS/128, 2), 256, 0, stream>>>((const short*)Mm, (const short*)cwt,
                                                        Amat2);
    k_conv  <<<dim3(BGRAPHS, 8), 128, 0, stream>>>(Amat2, emb, conv_b, cvo);
    k_fcxt_mfma<<<dim3(BGRAPHS/64, 11), 256, 0, stream>>>((const short*)cvo, (const short*)wxt, fxp);

    // head MLP (W-reuse batched: fc1 8 graphs/block, fc2out 2 graphs/block)
    k_fc1<<<dim3(BGRAPHS/8, 4), 256, 0, stream>>>(xc, fxp, fcxt_b, fc1_w, fc1_b, y1);
    k_fc2out<<<BGRAPHS/2, 256, 0, stream>>>(y1, fc2_w, fc2_b, out_w, out_b, (float*)d_out);
}

// Round 17
// 499.119 us; speedup vs baseline: 1.0273x; 1.0273x over previous
//
#include <hip/hip_runtime.h>
#include <hip/hip_bf16.h>

// Problem constants (from reference)
#define N_NODES 50000
#define N_EDGES 200000
#define BGRAPHS 512
#define F0c 78
#define H1c 10
#define HC1 780     // H1*F0 (logical)
#define HSTR 832    // padded row stride: 10 head blocks of 80 (78 data + 2 pad) + 32 K-pad cols
#define C2c 128
#define SEQc 1000
#define VOCABc 26
#define NFc 32
#define KWc 8
#define LOUTc 121
#define EMBc 128
#define KX 96       // padded cols for xpad (78 -> 96)
#define KXT 3872    // NF*LOUT = 32*121 -> 121 MFMA k-steps
#define MROWS 13312 // 512*26 one-hot rows = 104 * 128 exactly
#define KM 1024     // padded K for Amat GEMM (1000 -> 1024)
#define W2TF_N (25*8*64*8)   // w2t in MFMA-fragment order: [kstep 25][colgrp 8][lane 64][8 bf16]
#define NSCANB 196  // scan blocks: ceil(50000/256)

typedef __attribute__((ext_vector_type(8))) short short8;
typedef __attribute__((ext_vector_type(4))) float f32x4;
typedef unsigned short u16;

static constexpr size_t alignup(size_t x) { return (x + 255) & ~size_t(255); }

// -------- workspace layout (bytes) --------
// A_HBUF region holds xagg bf16 [N][10][80] = 80,000,000 B (region sized by HSTR, >= that).
// NOTE (R16): fusing agg1 into fuse12 to eliminate xagg REGRESSED (+10us): FETCH barely
// moved (40.7->38 MB; xagg re-reads were L3-resident), and the fusion serialized the
// xpad-gather latency with the MFMA phases. Keep agg1x separate (free-running waves).
static constexpr size_t A_HBUF = 0;
static constexpr size_t A_OUT1 = alignup(A_HBUF + size_t(N_NODES)*HSTR*2);   // (dead slot; xpad alias lives here)
static constexpr size_t A_H2   = alignup(A_OUT1 + size_t(N_NODES)*HSTR*2);   // f32  [N,128]
static constexpr size_t A_W2T  = alignup(A_H2   + size_t(N_NODES)*C2c*4);    // bf16 w2tf fragment layout (200 KB)
static constexpr size_t A_ALS1 = alignup(A_W2T  + size_t(C2c)*HSTR*2);
static constexpr size_t A_ALD1 = alignup(A_ALS1 + size_t(N_NODES)*H1c*4);
static constexpr size_t A_ALS2 = alignup(A_ALD1 + size_t(N_NODES)*H1c*4);
static constexpr size_t A_ALD2 = alignup(A_ALS2 + size_t(N_NODES)*4);
static constexpr size_t A_DEG  = alignup(A_ALD2 + size_t(N_NODES)*4);
static constexpr size_t A_OFFS = alignup(A_DEG  + size_t(N_NODES)*4);
static constexpr size_t A_CUR  = alignup(A_OFFS + size_t(N_NODES+1)*4);
static constexpr size_t A_CSRC = alignup(A_CUR  + size_t(N_NODES)*4);
static constexpr size_t A_XC   = alignup(A_CSRC + size_t(N_EDGES+N_NODES)*4);
static constexpr size_t A_Y1   = alignup(A_XC   + size_t(BGRAPHS)*256*4);
static constexpr size_t A_BOFF = alignup(A_Y1   + size_t(BGRAPHS)*1024*4);   // scan block-sums live here
static constexpr size_t A_BPAD = alignup(A_BOFF + size_t(BGRAPHS)*(VOCABc+1)*4);
static constexpr size_t A_WXT  = alignup(A_BPAD + size_t(HSTR)*4);           // bf16 [121][8][64][8] fragment order
static constexpr size_t A_FXP  = alignup(A_WXT  + size_t(C2c)*KXT*2);        // f32 [11][512][128]
static constexpr size_t A_W1HP = alignup(A_FXP  + size_t(11)*BGRAPHS*C2c*4); // bf16 [10][80][96]
static constexpr size_t A_WSD  = alignup(A_W1HP + size_t(10)*80*96*2);       // f32 [2][10][78]
static constexpr size_t A_CWT  = alignup(A_WSD  + size_t(2)*H1c*F0c*4);      // bf16 [2][256][1024] hi/lo conv_w^T
static constexpr size_t A_END  = alignup(A_CWT  + size_t(2)*256*KM*2);
static_assert(W2TF_N*2 <= size_t(C2c)*HSTR*2, "w2tf fits old slot");
static_assert((NSCANB+1)*4 <= BGRAPHS*(VOCABc+1)*4, "bsum fits A_BOFF slot");

// aliases inside xagg region (valid after k_fuse12 retires; xagg dead then):
static constexpr size_t A_HFIN = A_HBUF;                                        // f32 [N,128]
static constexpr size_t A_AMAT = alignup(A_HFIN + size_t(N_NODES)*C2c*4);       // f32 [13312][256]
static constexpr size_t A_CVO  = alignup(A_AMAT + size_t(MROWS)*256*4);         // bf16 [512][3872]
static constexpr size_t A_M    = alignup(A_CVO  + size_t(BGRAPHS)*KXT*2);       // bf16 [13312][1024] one-hot
static_assert(A_M + size_t(MROWS)*KM*2 <= size_t(N_NODES)*HSTR*2, "alias A overflow");
// alias inside out1 region (xpad dead before fuse12):
static constexpr size_t A_XPAD = A_OUT1;                                        // bf16 [N,96]
static_assert(size_t(N_NODES)*KX*2 <= size_t(N_NODES)*HSTR*2, "alias B overflow");

// -------- helpers --------
__device__ __forceinline__ float bflo(unsigned u) { return __uint_as_float(u << 16); }
__device__ __forceinline__ float bfhi(unsigned u) { return __uint_as_float(u & 0xffff0000u); }
__device__ __forceinline__ u16 f2bf(float v) {
    __hip_bfloat16 b = __float2bfloat16(v);
    return *(u16*)&b;
}

// async global->LDS, 16B per lane; LDS dest = wave-uniform base + lane*16
#define GLOAD16(g, l) __builtin_amdgcn_global_load_lds( \
    (const __attribute__((address_space(1))) void*)(g), \
    (__attribute__((address_space(3))) void*)(l), 16, 0, 0)

// ---------------- prep: deg init + conversions + folded attention vectors ----------------
__global__ void k_prep(const float* __restrict__ x, const float* __restrict__ W1,
                       const float* __restrict__ W2, const float* __restrict__ b1,
                       const float* __restrict__ fcxt_w, const float* __restrict__ conv_w,
                       const float* __restrict__ a_src1, const float* __restrict__ a_dst1,
                       __hip_bfloat16* __restrict__ xpad, __hip_bfloat16* __restrict__ w1hp,
                       u16* __restrict__ w2tf, float* __restrict__ bpad,
                       u16* __restrict__ wxt, float* __restrict__ wsd,
                       u16* __restrict__ cwt, int* __restrict__ deg) {
    int i = blockIdx.x*256 + threadIdx.x;
    const int R0 = N_NODES;
    const int R1 = R0 + N_NODES*KX;
    const int R2 = R1 + 10*80*96;
    const int R3 = R2 + W2TF_N;
    const int R4 = R3 + HSTR;
    const int R5 = R4 + C2c*KXT;
    const int R6 = R5 + 2*H1c*F0c;
    const int R7 = R6 + 256*KM;
    if (i < R0) {
        deg[i] = 1;   // self loop
    } else if (i < R1) {
        int t = i - R0; int n = t / KX, c = t - n*KX;
        xpad[t] = __float2bfloat16(c < F0c ? x[(size_t)n*F0c + c] : 0.f);
    } else if (i < R2) {
        int t = i - R1; int hh = t / 7680, rem = t - hh*7680;
        int j = rem / 96, k = rem - j*96;
        w1hp[t] = __float2bfloat16((j < F0c && k < F0c) ? W1[(size_t)k*HC1 + hh*F0c + j] : 0.f);
    } else if (i < R3) {
        // w2t in MFMA fragment order: frag index -> (kstep, colgrp, quad, m16), elem t in 0..7
        // value = w2t_logical[col = colgrp*16+m16][k = kstep*32 + quad*8 + t]
        // k-space is the 10x80 padded layout (head hh = k/80, in-head col cc = k%80; cc>=78 -> 0)
        int t = i - R2; int frag = t >> 3, tt = t & 7;
        int m16 = frag & 15, quad = (frag >> 4) & 3, cbg = (frag >> 6) & 7, kstep = frag >> 9;
        int col = cbg*16 + m16;
        int k = kstep*32 + quad*8 + tt;
        int hh = k / 80, cc = k - hh*80;
        w2tf[t] = f2bf((cc < F0c) ? W2[(size_t)(hh*F0c + cc)*C2c + col] : 0.f);
    } else if (i < R4) {
        int p = i - R3; int hh = p / 80, cc = p - hh*80;
        bpad[p] = (hh < H1c && cc < F0c) ? b1[hh*F0c + cc] : 0.f;
    } else if (i < R5) {
        // fc_xt weights in MFMA fragment order: [kt 121][ct 8][lane 64][8 bf16]
        // value[t] = fcxt_w[(kt*32 + quad*8 + t)*C2c + (ct*16 + m16)]
        int t = i - R4; int frag = t >> 3, tt = t & 7;
        int lane = frag & 63, m16 = lane & 15, quad = lane >> 4;
        int ct = (frag >> 6) & 7, kt = frag >> 9;
        wxt[t] = f2bf(fcxt_w[(size_t)(kt*32 + quad*8 + tt)*C2c + (ct*16 + m16)]);
    } else if (i < R6) {
        int t = i - R5; int sd = t / (H1c*F0c), rem = t - sd*(H1c*F0c);
        int hh = rem / F0c, c = rem - hh*F0c;
        const float* a = sd ? a_dst1 : a_src1;
        float v = 0.f;
        for (int j = 0; j < F0c; j++) v += W1[(size_t)c*HC1 + hh*F0c + j] * a[hh*F0c + j];
        wsd[t] = v;
    } else if (i < R7) {
        // conv_w^T hi/lo split: cwt[0][col][i] = bf16(v), cwt[1][col][i] = bf16(v - f32(hi))
        int t = i - R6; int col = t >> 10, ii = t & (KM-1);
        int o = col >> 3, k = col & 7;
        float v = (ii < SEQc) ? conv_w[((size_t)o*SEQc + ii)*KWc + k] : 0.f;
        u16 h = f2bf(v);
        float hv = __uint_as_float((unsigned)h << 16);
        cwt[(size_t)col*KM + ii] = h;
        cwt[(size_t)256*KM + (size_t)col*KM + ii] = f2bf(v - hv);
    }
}
#define PREP_TOTAL (N_NODES + N_NODES*KX + 10*80*96 + W2TF_N + HSTR + C2c*KXT + 2*H1c*F0c + 256*KM)

// ---------------- CSR build ----------------
__global__ void k_count(const int* __restrict__ ei, int* deg) {
    int i = blockIdx.x*256 + threadIdx.x;
    if (i < N_EDGES) atomicAdd(&deg[ei[N_EDGES + i]], 1);
}
// Multi-block exclusive scan (R13: replaced single-block scan, -37us). Integer-exact.
__global__ void k_scan1(const int* __restrict__ deg, int* __restrict__ offs,
                        int* __restrict__ bsum, int n) {
    int b = blockIdx.x, tid = threadIdx.x, lane = tid & 63, wid = tid >> 6;
    int i = b*256 + tid;
    int v0 = (i < n) ? deg[i] : 0;
    int v = v0;
    for (int d = 1; d < 64; d <<= 1) { int t = __shfl_up(v, d, 64); if (lane >= d) v += t; }
    __shared__ int ws[4];
    if (lane == 63) ws[wid] = v;
    __syncthreads();
    if (tid == 0) {
        int r = 0;
        #pragma unroll
        for (int w = 0; w < 4; w++) { int t = ws[w]; ws[w] = r; r += t; }
        bsum[b] = r;
    }
    __syncthreads();
    if (i < n) offs[i] = ws[wid] + (v - v0);   // exclusive local prefix
}
__global__ void k_scan2(int* __restrict__ bsum, int nb) {
    __shared__ int s[NSCANB];
    int tid = threadIdx.x;
    for (int i = tid; i < nb; i += 256) s[i] = bsum[i];
    __syncthreads();
    if (tid == 0) {
        int r = 0;
        for (int b = 0; b < nb; b++) { int t = s[b]; s[b] = r; r += t; }
        bsum[nb] = r;                           // total
    }
    __syncthreads();
    for (int i = tid; i < nb; i += 256) bsum[i] = s[i];
}
__global__ void k_scan3(const int* __restrict__ bsum, int* __restrict__ offs,
                        int* __restrict__ cur, int n, int nb) {
    int b = blockIdx.x, i = b*256 + threadIdx.x;
    if (i < n) {
        int o = offs[i] + bsum[b];
        offs[i] = o; cur[i] = o;
    } else if (i == n) {
        offs[n] = bsum[nb];
    }
}
__global__ void k_fill(const int* __restrict__ ei, int* cur, int* __restrict__ csrc) {
    int i = blockIdx.x*256 + threadIdx.x;
    if (i < N_EDGES) {
        int s = ei[i], d = ei[N_EDGES + i];
        int p = atomicAdd(&cur[d], 1);
        csrc[p] = s;
    } else if (i < N_EDGES + N_NODES) {
        int n = i - N_EDGES;
        int p = atomicAdd(&cur[n], 1);
        csrc[p] = n;
    }
}
// determinize: sort each CSR segment (atomic fill order varies run-to-run)
__global__ void k_sortcsr(const int* __restrict__ offs, int* __restrict__ csrc) {
    int n = blockIdx.x*256 + threadIdx.x;
    if (n >= N_NODES) return;
    int s = offs[n], e = offs[n+1];
    for (int i = s + 1; i < e; i++) {
        int v = csrc[i];
        int j = i - 1;
        while (j >= s && csrc[j] > v) { csrc[j+1] = csrc[j]; j--; }
        csrc[j+1] = v;
    }
}

// ---------------- layer-1 attention logits, direct from x: als = x @ (W1_h a_h) ----------------
__global__ void k_att1x(const float* __restrict__ x, const float* __restrict__ wsd,
                        float* __restrict__ als, float* __restrict__ ald) {
    int i = blockIdx.x*256 + threadIdx.x;
    if (i >= N_NODES*H1c) return;
    int n = i / H1c, hh = i - n*H1c;
    const float* xr = x + (size_t)n*F0c;
    const float* ws = wsd + hh*F0c;
    const float* wd = wsd + H1c*F0c + hh*F0c;
    float s1 = 0.f, s2 = 0.f;
    for (int c = 0; c < F0c; c++) { float v = xr[c]; s1 += v*ws[c]; s2 += v*wd[c]; }
    als[i] = s1; ald[i] = s2;
}

// ---------------- layer-1 aggregation in x-space: xagg[n,hh,80] = sum alpha * x[src] ----------------
// FINAL (R13/R15 config, measured best): 1-wave blocks, free-running. R10 (block-barrier
// packing, -14us), R14 (barrier-free packing, neutral), R16 (fusion into fuse12, +10us)
// all established this gather is memory-latency-bound and best left maximally independent.
__global__ void k_agg1x(const unsigned* __restrict__ xpu, const float* __restrict__ als,
                        const float* __restrict__ ald, const int* __restrict__ offs,
                        const int* __restrict__ csrc, unsigned* __restrict__ xaggu) {
    constexpr int H = H1c;
    int dn = blockIdx.x, lane = threadIdx.x;   // 64
    int s = offs[dn], e = offs[dn+1], deg = e - s;
    __shared__ float wexp[64*H];               // 2560 B
    __shared__ int   ssrc[64];
    __shared__ float ms[H], dinv_s[H];

    if (deg <= 64) {
        if (lane < deg) ssrc[lane] = csrc[s + lane];
        __syncthreads();
        for (int idx = lane; idx < deg*H; idx += 64) {
            int j = idx / H, hh = idx - j*H;
            float al = als[(size_t)ssrc[j]*H + hh] + ald[(size_t)dn*H + hh];
            wexp[idx] = (al >= 0.f) ? al : 0.2f*al;
        }
        __syncthreads();
        if (lane < H) {
            float m = -1e30f;
            for (int j = 0; j < deg; j++) m = fmaxf(m, wexp[j*H + lane]);
            float den = 0.f;
            for (int j = 0; j < deg; j++) den += __expf(wexp[j*H + lane] - m);
            ms[lane] = m; dinv_s[lane] = 1.f/(den + 1e-16f);
        }
        __syncthreads();
        for (int idx = lane; idx < deg*H; idx += 64) {
            int hh = idx % H;
            wexp[idx] = __expf(wexp[idx] - ms[hh]) * dinv_s[hh];
        }
        __syncthreads();
        if (lane < 40) {                       // uint c covers x cols 2c,2c+1 (cols 0..79)
            float accL[H], accH[H];
            #pragma unroll
            for (int hh = 0; hh < H; hh++) { accL[hh] = 0.f; accH[hh] = 0.f; }
            int j = 0;
            for (; j + 1 < deg; j += 2) {
                unsigned ua = xpu[(size_t)ssrc[j]*48 + lane];
                unsigned ub = xpu[(size_t)ssrc[j+1]*48 + lane];
                float a0 = bflo(ua), a1 = bfhi(ua), b0 = bflo(ub), b1 = bfhi(ub);
                #pragma unroll
                for (int hh = 0; hh < H; hh++) {
                    float wA = wexp[j*H + hh], wB = wexp[(j+1)*H + hh];
                    accL[hh] += wA*a0 + wB*b0;
                    accH[hh] += wA*a1 + wB*b1;
                }
            }
            if (j < deg) {
                unsigned ua = xpu[(size_t)ssrc[j]*48 + lane];
                float a0 = bflo(ua), a1 = bfhi(ua);
                #pragma unroll
                for (int hh = 0; hh < H; hh++) {
                    float wA = wexp[j*H + hh];
                    accL[hh] += wA*a0;
                    accH[hh] += wA*a1;
                }
            }
            #pragma unroll
            for (int hh = 0; hh < H; hh++) {
                unsigned p = (unsigned)f2bf(accL[hh]) | ((unsigned)f2bf(accH[hh]) << 16);
                xaggu[((size_t)dn*H + hh)*40 + lane] = p;
            }
        }
    } else {
        // fallback deg>64 (practically never): recompute alpha inline, guaranteed correct
        if (lane < H) {
            float adv = ald[(size_t)dn*H + lane];
            float m = -1e30f;
            for (int j = s; j < e; j++) {
                float al = als[(size_t)csrc[j]*H + lane] + adv;
                al = (al >= 0.f) ? al : 0.2f*al;
                m = fmaxf(m, al);
            }
            float den = 0.f;
            for (int j = s; j < e; j++) {
                float al = als[(size_t)csrc[j]*H + lane] + adv;
                al = (al >= 0.f) ? al : 0.2f*al;
                den += __expf(al - m);
            }
            ms[lane] = m; dinv_s[lane] = 1.f/(den + 1e-16f);
        }
        __syncthreads();
        if (lane < 40) {
            float accL[H], accH[H];
            #pragma unroll
            for (int hh = 0; hh < H; hh++) { accL[hh] = 0.f; accH[hh] = 0.f; }
            for (int j = s; j < e; j++) {
                int sj = csrc[j];
                unsigned ua = xpu[(size_t)sj*48 + lane];
                float a0 = bflo(ua), a1 = bfhi(ua);
                #pragma unroll
                for (int hh = 0; hh < H; hh++) {
                    float al = als[(size_t)sj*H + hh] + ald[(size_t)dn*H + hh];
                    al = (al >= 0.f) ? al : 0.2f*al;
                    float a = __expf(al - ms[hh]) * dinv_s[hh];
                    accL[hh] += a*a0;
                    accH[hh] += a*a1;
                }
            }
            #pragma unroll
            for (int hh = 0; hh < H; hh++) {
                unsigned p = (unsigned)f2bf(accL[hh]) | ((unsigned)f2bf(accH[hh]) << 16);
                xaggu[((size_t)dn*H + hh)*40 + lane] = p;
            }
        }
    }
}

// ---------------- FUSED v5 (R9/R15 best, ~75.5us): 16-row blocks, serial per-head loads ----------------
// Residency design notes (R4-R16 lessons, keep as-is):
// - 16-row blocks, LDS 26,624 B.
// - launch_bounds(256,8): VGPR cap 64; serial per-head loads keep live set ~60, no spills.
// - min-waves 6 clamps allocator to 40 VGPR -> scratch spills (+12-22 MB HBM writes). Avoid.
// - Occupancy counter stays ~36% regardless of LDS/VGPR headroom; 6x scheduling attempts
//   null/negative. FETCH 40.7 MB is xpad/xagg L3-latency exposure; fusing agg1 in (R16)
//   did not reduce it and serialized the gather -> +10us. Parked at ~75us.
__global__ void __launch_bounds__(256, 8)
k_fuse12(const short* __restrict__ xagg, const short* __restrict__ w1hp,
         const float* __restrict__ bpad, const short* __restrict__ w2tf,
         const float* __restrict__ a_src2, const float* __restrict__ a_dst2,
         float* __restrict__ Cout, float* __restrict__ als2, float* __restrict__ ald2) {
    __shared__ __attribute__((aligned(16))) short As[16*832];      // 26,624 B; whole LDS block
    int tid = threadIdx.x;
    int wave = tid >> 6, lane = tid & 63;                          // 4 waves
    int m16 = lane & 15, quad = lane >> 4;
    int blockrow = blockIdx.x * 16;                                // 3125 blocks, exact

    // ---- phase 1: per-head 80x80 GEMM + bias + ELU -> As (swizzled bf16) ----
    {
        int hg = wave;                           // heads {hg, hg+4, hg+8 if hg<2}
        int rowc = min(blockrow + m16, N_NODES-1);
        for (int hh = hg; hh < H1c; hh += 4) {
            const short8* arow = (const short8*)(xagg + ((size_t)rowc*H1c + hh)*80);
            f32x4 acc1[5];
            #pragma unroll
            for (int ct = 0; ct < 5; ct++) acc1[ct] = (f32x4){0.f,0.f,0.f,0.f};
            #pragma unroll
            for (int kt = 0; kt < 3; kt++) {
                short8 af = arow[kt*4 + quad];   // kt=2,quad>=2 overreads: B zeros neutralize
                #pragma unroll
                for (int ct = 0; ct < 5; ct++) {
                    const short8* brow = (const short8*)(w1hp + (size_t)(hh*80 + ct*16 + m16)*96);
                    acc1[ct] = __builtin_amdgcn_mfma_f32_16x16x32_bf16(af, brow[kt*4 + quad],
                                                                      acc1[ct], 0, 0, 0);
                }
            }
            #pragma unroll
            for (int ct = 0; ct < 5; ct++) {
                int col = hh*80 + ct*16 + m16;
                float bv = bpad[col];
                #pragma unroll
                for (int r = 0; r < 4; r++) {
                    int rl = quad*4 + r;
                    float v = acc1[ct][r] + bv;
                    v = (v > 0.f) ? v : (__expf(v) - 1.f);
                    *(u16*)((char*)As + rl*1664 + ((col*2) ^ ((rl & 7) << 4))) = f2bf(v);
                }
            }
        }
    }
    __syncthreads();   // As complete (cols 800..831 never read: K-loop stops at 800)

    // ---- phase 2: gemm2, A from LDS, B direct from global fragment layout; no barriers ----
    int cg = wave;                               // 4 col-groups of 32
    f32x4 acc[2];
    acc[0] = (f32x4){0.f,0.f,0.f,0.f};
    acc[1] = (f32x4){0.f,0.f,0.f,0.f};
    int S = (m16 & 7) << 4;                      // read-side swizzle (row&7 == m16&7)
    const char* asRow = (const char*)As + (size_t)m16*1664;
    const short8* bp = (const short8*)w2tf;
    #pragma unroll 5
    for (int kstep = 0; kstep < 25; kstep++) {
        short8 af = *(const short8*)(asRow + ((kstep*64 + quad*16) ^ S));
        short8 b0 = bp[(size_t)(kstep*8 + cg*2    )*64 + lane];
        short8 b1 = bp[(size_t)(kstep*8 + cg*2 + 1)*64 + lane];
        acc[0] = __builtin_amdgcn_mfma_f32_16x16x32_bf16(af, b0, acc[0], 0, 0, 0);
        acc[1] = __builtin_amdgcn_mfma_f32_16x16x32_bf16(af, b1, acc[1], 0, 0, 0);
    }

    // ---- epilogue: C-write (global; does not touch As) ----
    float asv[2], adv[2];
    #pragma unroll
    for (int ct = 0; ct < 2; ct++) {
        asv[ct] = a_src2[cg*32 + ct*16 + m16];
        adv[ct] = a_dst2[cg*32 + ct*16 + m16];
    }
    #pragma unroll
    for (int ct = 0; ct < 2; ct++) {
        int col = cg*32 + ct*16 + m16;
        #pragma unroll
        for (int r = 0; r < 4; r++) {
            int orow = blockrow + quad*4 + r;
            if (orow < N_NODES) Cout[(size_t)orow*C2c + col] = acc[ct][r];
        }
    }

    // ---- att2 fold: partials overlaid on As (dead after phase 2) ----
    __syncthreads();                             // all As reads complete before reuse
    float* sred  = (float*)As;                   // [16][4]
    float* sredd = sred + 64;                    // [16][4]
    #pragma unroll
    for (int r = 0; r < 4; r++) {
        float s1 = 0.f, s2 = 0.f;
        #pragma unroll
        for (int ct = 0; ct < 2; ct++) { s1 += acc[ct][r]*asv[ct]; s2 += acc[ct][r]*adv[ct]; }
        #pragma unroll
        for (int d = 1; d < 16; d <<= 1) { s1 += __shfl_xor(s1, d, 64); s2 += __shfl_xor(s2, d, 64); }
        if (m16 == 0) {
            int rl = quad*4 + r;
            sred[rl*4 + cg] = s1;
            sredd[rl*4 + cg] = s2;
        }
    }
    __syncthreads();
    if (tid < 16) {
        int orow = blockrow + tid;
        if (orow < N_NODES) {
            als2[orow] = sred[tid*4+0] + sred[tid*4+1] + sred[tid*4+2] + sred[tid*4+3];
            ald2[orow] = sredd[tid*4+0] + sredd[tid*4+1] + sredd[tid*4+2] + sredd[tid*4+3];
        }
    }
}

// ---------------- GAT layer-2 aggregation (H=1, C=128 f32) ----------------
// FINAL (R13/R15 config): 1-wave blocks; gather latency-bound (R10/R14/R16 established).
__global__ void k_agg2(const float* __restrict__ h2, const float* __restrict__ als,
                       const float* __restrict__ ald, const int* __restrict__ offs,
                       const int* __restrict__ csrc, const float* __restrict__ b2,
                       float* __restrict__ out) {
    int dn = blockIdx.x, lane = threadIdx.x;   // 64
    int s = offs[dn], e = offs[dn+1], deg = e - s;
    __shared__ float wexp[128];
    __shared__ int ssrc[128];

    if (deg <= 128) {
        float adv = ald[dn];
        for (int j = lane; j < deg; j += 64) {
            int sj = csrc[s + j];
            ssrc[j] = sj;
            float al = als[sj] + adv;
            wexp[j] = (al >= 0.f) ? al : 0.2f*al;
        }
        __syncthreads();
        float m = -1e30f;
        for (int j = lane; j < deg; j += 64) m = fmaxf(m, wexp[j]);
        #pragma unroll
        for (int d = 32; d > 0; d >>= 1) m = fmaxf(m, __shfl_xor(m, d, 64));
        __syncthreads();
        float den = 0.f;
        for (int j = lane; j < deg; j += 64) {
            float ex = __expf(wexp[j] - m);
            wexp[j] = ex;
            den += ex;
        }
        #pragma unroll
        for (int d = 32; d > 0; d >>= 1) den += __shfl_xor(den, d, 64);
        float dinv = 1.f/(den + 1e-16f);
        __syncthreads();
        float2 acc = {0.f, 0.f};
        for (int j = 0; j < deg; j++) {
            float alpha = wexp[j] * dinv;
            float2 v = ((const float2*)(h2 + (size_t)ssrc[j]*C2c))[lane];
            acc.x += alpha*v.x; acc.y += alpha*v.y;
        }
        float2 o;
        o.x = fmaxf(acc.x + b2[2*lane], 0.f);
        o.y = fmaxf(acc.y + b2[2*lane+1], 0.f);
        ((float2*)(out + (size_t)dn*C2c))[lane] = o;
    } else {
        __shared__ float sm[2];
        if (lane == 0) {
            float adv = ald[dn];
            float m = -1e30f;
            for (int j = s; j < e; j++) {
                float al = als[csrc[j]] + adv;
                al = (al >= 0.f) ? al : 0.2f*al;
                m = fmaxf(m, al);
            }
            float den = 0.f;
            for (int j = s; j < e; j++) {
                float al = als[csrc[j]] + adv;
                al = (al >= 0.f) ? al : 0.2f*al;
                den += __expf(al - m);
            }
            sm[0] = m; sm[1] = 1.f/(den + 1e-16f);
        }
        __syncthreads();
        float m = sm[0], dinv = sm[1], adv = ald[dn];
        float2 acc = {0.f, 0.f};
        for (int j = s; j < e; j++) {
            int sj = csrc[j];
            float al = als[sj] + adv;
            al = (al >= 0.f) ? al : 0.2f*al;
            float alpha = __expf(al - m) * dinv;
            float2 v = ((const float2*)(h2 + (size_t)sj*C2c))[lane];
            acc.x += alpha*v.x; acc.y += alpha*v.y;
        }
        float2 o;
        o.x = fmaxf(acc.x + b2[2*lane], 0.f);
        o.y = fmaxf(acc.y + b2[2*lane+1], 0.f);
        ((float2*)(out + (size_t)dn*C2c))[lane] = o;
    }
}

// ---------------- pool + fc_g1 merged (g stays in LDS) ----------------
__global__ void k_poolfcg(const float* __restrict__ hf, const int* __restrict__ batch,
                          const float* __restrict__ W, const float* __restrict__ bias,
                          float* __restrict__ xc) {
    int b = blockIdx.x, tid = threadIdx.x;    // 128
    __shared__ int se[2];
    __shared__ float gs[C2c];
    if (tid < 2) {
        int key = b + tid;
        int lo = 0, hi = N_NODES;
        while (lo < hi) { int mid = (lo+hi) >> 1; if (batch[mid] < key) lo = mid+1; else hi = mid; }
        se[tid] = lo;
    }
    __syncthreads();
    int s = se[0], e = se[1];
    float m = -1e30f;
    for (int n = s; n < e; n++) m = fmaxf(m, hf[(size_t)n*C2c + tid]);
    gs[tid] = m;
    __syncthreads();
    float acc = bias[tid];
    for (int k = 0; k < C2c; k++) acc += gs[k] * W[k*C2c + tid];
    xc[b*256 + tid] = fmaxf(acc, 0.f);
}

// ---------------- conv path ----------------
// build one-hot matrix M[(b*26+t)][i] = (target[b,i]==t), bf16, K padded to 1024.
__global__ void k_buildM(const int* __restrict__ target, u16* __restrict__ Mm) {
    int b = blockIdx.x, tid = threadIdx.x;    // 256
    short8 z = (short8){0,0,0,0,0,0,0,0};
    short8* base = (short8*)(Mm + (size_t)b*VOCABc*KM);
    for (int i = tid; i < VOCABc*KM/8; i += 256) base[i] = z;
    __syncthreads();
    for (int i = tid; i < SEQc; i += 256) {
        int t = target[(size_t)b*SEQc + i];
        Mm[((size_t)b*VOCABc + t)*KM + i] = (u16)0x3F80;   // bf16 1.0
    }
}

// Amat via MFMA: A2[13312][256] = M[13312][1024] @ cwt^T (hi) + M @ cwt^T (lo).
__global__ void __launch_bounds__(256, 1)
k_amat_mfma(const short* __restrict__ Mm, const short* __restrict__ cwt,
            float* __restrict__ A2) {
    __shared__ __attribute__((aligned(16))) short As[2][128*64];
    __shared__ __attribute__((aligned(16))) short Bh[2][128*64];
    __shared__ __attribute__((aligned(16))) short Bl[2][128*64];
    int tid = threadIdx.x;
    int wave = tid >> 6, lane = tid & 63;
    int m16 = lane & 15, quad = lane >> 4;
    int blockrow = blockIdx.x * 128;       // 104 row-tiles
    int colbase  = blockIdx.y * 128;       // 2 col-tiles

    size_t aoff[4], bo[4];
    #pragma unroll
    for (int i = 0; i < 4; i++) {
        int c = wave*256 + i*64 + lane;
        int row = c >> 3;
        int cb  = (c & 7) << 4;
        int srcb = cb ^ ((row & 7) << 4);
        aoff[i] = (size_t)(blockrow + row) * (KM*2) + srcb;
        bo[i]   = (size_t)(colbase  + row) * (KM*2) + srcb;
    }
    const char* hbase = (const char*)cwt;
    const char* lbase = (const char*)(cwt + (size_t)256*KM);

    f32x4 acc[2][8];
    #pragma unroll
    for (int wr = 0; wr < 2; wr++)
        #pragma unroll
        for (int ct = 0; ct < 8; ct++) acc[wr][ct] = (f32x4){0.f,0.f,0.f,0.f};

    #pragma unroll
    for (int i = 0; i < 4; i++) {
        GLOAD16((const char*)Mm + aoff[i], &As[0][(wave*256 + i*64)*8]);
        GLOAD16(hbase + bo[i],             &Bh[0][(wave*256 + i*64)*8]);
        GLOAD16(lbase + bo[i],             &Bl[0][(wave*256 + i*64)*8]);
    }
    __syncthreads();

    int cur = 0;
    int S = (m16 & 7) << 4;
    for (int s = 0; s < KM/64; s++) {
        if (s + 1 < KM/64) {
            size_t kb = (size_t)(s + 1) * 128;
            #pragma unroll
            for (int i = 0; i < 4; i++) {
                GLOAD16((const char*)Mm + aoff[i] + kb, &As[cur^1][(wave*256 + i*64)*8]);
                GLOAD16(hbase + bo[i] + kb,             &Bh[cur^1][(wave*256 + i*64)*8]);
                GLOAD16(lbase + bo[i] + kb,             &Bl[cur^1][(wave*256 + i*64)*8]);
            }
        }
        const char* asBase = (const char*)&As[cur][0];
        const char* bhBase = (const char*)&Bh[cur][0];
        const char* blBase = (const char*)&Bl[cur][0];
        #pragma unroll
        for (int kk = 0; kk < 2; kk++) {
            int kb2 = (kk*64 + quad*16) ^ S;
            short8 af[2];
            #pragma unroll
            for (int wr = 0; wr < 2; wr++) {
                int row = wave*32 + wr*16 + m16;
                af[wr] = *(const short8*)(asBase + row*128 + kb2);
            }
            #pragma unroll
            for (int ct = 0; ct < 8; ct++) {
                int col = ct*16 + m16;
                short8 bhv = *(const short8*)(bhBase + col*128 + kb2);
                short8 blv = *(const short8*)(blBase + col*128 + kb2);
                acc[0][ct] = __builtin_amdgcn_mfma_f32_16x16x32_bf16(af[0], bhv, acc[0][ct], 0, 0, 0);
                acc[1][ct] = __builtin_amdgcn_mfma_f32_16x16x32_bf16(af[1], bhv, acc[1][ct], 0, 0, 0);
                acc[0][ct] = __builtin_amdgcn_mfma_f32_16x16x32_bf16(af[0], blv, acc[0][ct], 0, 0, 0);
                acc[1][ct] = __builtin_amdgcn_mfma_f32_16x16x32_bf16(af[1], blv, acc[1][ct], 0, 0, 0);
            }
        }
        __syncthreads();
        cur ^= 1;
    }

    #pragma unroll
    for (int wr = 0; wr < 2; wr++) {
        int rowbase = blockrow + wave*32 + wr*16 + quad*4;
        #pragma unroll
        for (int ct = 0; ct < 8; ct++) {
            int col = colbase + ct*16 + m16;
            #pragma unroll
            for (int r = 0; r < 4; r++) {
                A2[(size_t)(rowbase + r)*256 + col] = acc[wr][ct][r];
            }
        }
    }
}

__global__ void __launch_bounds__(128, 4)
k_conv(const float* __restrict__ A2, const float* __restrict__ emb,
       const float* __restrict__ convb, u16* __restrict__ convout) {
    int b = blockIdx.x, og = blockIdx.y;      // og in 0..7 -> o base og*4
    int tid = threadIdx.x;                    // 128
    __shared__ float embs[VOCABc*EMBc];       // 13.3 KB
    __shared__ float arow[4*VOCABc*KWc];      // 3.3 KB
    for (int i = tid; i < VOCABc*EMBc; i += 128) embs[i] = emb[i];
    for (int i = tid; i < 4*VOCABc*KWc; i += 128) {
        int o2 = i / (VOCABc*KWc);
        int rem = i - o2*(VOCABc*KWc);        // t*8+k
        int t = rem >> 3, k = rem & 7;
        arow[i] = A2[((size_t)b*VOCABc + t)*256 + (og*4 + o2)*8 + k];
    }
    __syncthreads();
    if (tid < LOUTc) {
        float a0 = convb[og*4+0], a1 = convb[og*4+1], a2 = convb[og*4+2], a3 = convb[og*4+3];
        for (int t = 0; t < VOCABc; t++) {
            #pragma unroll
            for (int k = 0; k < KWc; k++) {
                float ev = embs[t*EMBc + tid + k];
                a0 += arow[0*(VOCABc*KWc) + t*KWc + k] * ev;
                a1 += arow[1*(VOCABc*KWc) + t*KWc + k] * ev;
                a2 += arow[2*(VOCABc*KWc) + t*KWc + k] * ev;
                a3 += arow[3*(VOCABc*KWc) + t*KWc + k] * ev;
            }
        }
        size_t base = (size_t)b*KXT + (og*4)*LOUTc + tid;
        convout[base            ] = f2bf(fmaxf(a0, 0.f));
        convout[base +   LOUTc  ] = f2bf(fmaxf(a1, 0.f));
        convout[base + 2*LOUTc  ] = f2bf(fmaxf(a2, 0.f));
        convout[base + 3*LOUTc  ] = f2bf(fmaxf(a3, 0.f));
    }
}
// fc_xt partials via MFMA; B (wxt) in fragment order -> fully coalesced 16B/lane loads.
__global__ void k_fcxt_mfma(const short* __restrict__ cvo, const short* __restrict__ wxt,
                            float* __restrict__ fxp) {
    int wave = threadIdx.x >> 6, lane = threadIdx.x & 63;
    int m16 = lane & 15, quad = lane >> 4;
    int r0 = blockIdx.x*64 + wave*16;      // 512 rows = 8 blocks * 64
    int kt0 = blockIdx.y*11;               // 121 k-steps = 11 chunks * 11
    const short8* arow = (const short8*)(cvo + (size_t)(r0 + m16)*KXT);
    const short8* bp = (const short8*)wxt;
    f32x4 acc[8];
    #pragma unroll
    for (int ct = 0; ct < 8; ct++) acc[ct] = (f32x4){0.f,0.f,0.f,0.f};
    for (int kt = kt0; kt < kt0 + 11; kt++) {
        short8 af = arow[kt*4 + quad];
        #pragma unroll
        for (int ct = 0; ct < 8; ct++) {
            short8 bf = bp[(size_t)(kt*8 + ct)*64 + lane];
            acc[ct] = __builtin_amdgcn_mfma_f32_16x16x32_bf16(af, bf, acc[ct], 0, 0, 0);
        }
    }
    #pragma unroll
    for (int ct = 0; ct < 8; ct++) {
        int col = ct*16 + m16;
        #pragma unroll
        for (int r = 0; r < 4; r++) {
            int row = r0 + quad*4 + r;
            fxp[((size_t)blockIdx.y*BGRAPHS + row)*C2c + col] = acc[ct][r];
        }
    }
}

// ---------------- head MLP ----------------
// fc1 v2: 8 graphs per block x 4 col-quarters. W traffic 512 MB -> 64 MB. Bit-identical y1.
__global__ void __launch_bounds__(256, 4)
k_fc1(const float* __restrict__ xc, const float* __restrict__ fxp,
      const float* __restrict__ fcxt_b, const float* __restrict__ W,
      const float* __restrict__ bias, float* __restrict__ y1) {
    int g0 = blockIdx.x * 8;                  // 64 graph-groups
    int colq = blockIdx.y;                    // 4 col-quarters
    int tid = threadIdx.x;                    // 256
    __shared__ float xs[8][256];              // 8 KB
    for (int idx = tid; idx < 8*256; idx += 256) {
        int g = idx >> 8, k = idx & 255;
        int b = g0 + g;
        float v;
        if (k < 128) {
            v = xc[b*256 + k];
        } else {
            int col = k - 128;
            float s = fcxt_b[col];
            #pragma unroll
            for (int q = 0; q < 11; q++) s += fxp[((size_t)q*BGRAPHS + b)*C2c + col];
            v = s;
        }
        xs[g][k] = v;
    }
    __syncthreads();
    int col = colq*256 + tid;
    float a[8];
    #pragma unroll
    for (int g = 0; g < 8; g++) a[g] = bias[col];
    for (int k = 0; k < 256; k++) {
        float w = W[(size_t)k*1024 + col];    // coalesced; xs[g][k] is LDS broadcast
        #pragma unroll
        for (int g = 0; g < 8; g++) a[g] += xs[g][k] * w;
    }
    #pragma unroll
    for (int g = 0; g < 8; g++)
        y1[(size_t)(g0+g)*1024 + col] = fmaxf(a[g], 0.f);
}
// fc2out v2: 2 graphs per block. Bit-identical out.
__global__ void __launch_bounds__(256, 4)
k_fc2out(const float* __restrict__ y1, const float* __restrict__ W,
         const float* __restrict__ bias, const float* __restrict__ ow,
         const float* __restrict__ ob, float* __restrict__ out) {
    int g0 = blockIdx.x * 2;                  // 256 graph-groups
    int tid = threadIdx.x;                    // 256
    int lane = tid & 63, wid = tid >> 6;
    __shared__ float ys[2][1024];             // 8 KB
    __shared__ float wsum[2][4];
    for (int i = tid; i < 2048; i += 256)
        ys[i >> 10][i & 1023] = y1[(size_t)(g0 + (i >> 10))*1024 + (i & 1023)];
    __syncthreads();
    float acc0 = bias[tid], acc1 = bias[tid];
    for (int k = 0; k < 1024; k++) {
        float w = W[(size_t)k*256 + tid];     // coalesced; ys[g][k] is LDS broadcast
        acc0 += ys[0][k] * w;
        acc1 += ys[1][k] * w;
    }
    float v0 = fmaxf(acc0, 0.f) * ow[tid];
    float v1 = fmaxf(acc1, 0.f) * ow[tid];
    #pragma unroll
    for (int d = 32; d > 0; d >>= 1) { v0 += __shfl_xor(v0, d, 64); v1 += __shfl_xor(v1, d, 64); }
    if (lane == 0) { wsum[0][wid] = v0; wsum[1][wid] = v1; }
    __syncthreads();
    if (tid < 2)
        out[g0 + tid] = wsum[tid][0] + wsum[tid][1] + wsum[tid][2] + wsum[tid][3] + ob[0];
}

extern "C" void kernel_launch(void* const* d_in, const int* in_sizes, int n_in,
                              void* d_out, int out_size, void* d_ws, size_t ws_size,
                              hipStream_t stream) {
    (void)in_sizes; (void)n_in; (void)out_size;
    if (ws_size < A_END) return;   // guard: clean numeric-fail if ws too small

    const float* x       = (const float*)d_in[0];
    const int*   ei      = (const int*)  d_in[1];
    const int*   batch   = (const int*)  d_in[2];
    const int*   target  = (const int*)  d_in[3];
    const float* W1      = (const float*)d_in[4];
    const float* a_src1  = (const float*)d_in[5];
    const float* a_dst1  = (const float*)d_in[6];
    const float* b1      = (const float*)d_in[7];
    const float* W2      = (const float*)d_in[8];
    const float* a_src2  = (const float*)d_in[9];
    const float* a_dst2  = (const float*)d_in[10];
    const float* b2      = (const float*)d_in[11];
    const float* fcg_w   = (const float*)d_in[12];
    const float* fcg_b   = (const float*)d_in[13];
    const float* emb     = (const float*)d_in[14];
    const float* conv_w  = (const float*)d_in[15];
    const float* conv_b  = (const float*)d_in[16];
    const float* fcxt_w  = (const float*)d_in[17];
    const float* fcxt_b  = (const float*)d_in[18];
    const float* fc1_w   = (const float*)d_in[19];
    const float* fc1_b   = (const float*)d_in[20];
    const float* fc2_w   = (const float*)d_in[21];
    const float* fc2_b   = (const float*)d_in[22];
    const float* out_w   = (const float*)d_in[23];
    const float* out_b   = (const float*)d_in[24];

    char* wsb = (char*)d_ws;
    u16*   xagg  = (u16*)  (wsb + A_HBUF);
    float* h2    = (float*)(wsb + A_H2);
    u16*   w2tf  = (u16*)  (wsb + A_W2T);
    float* als1  = (float*)(wsb + A_ALS1);
    float* ald1  = (float*)(wsb + A_ALD1);
    float* als2  = (float*)(wsb + A_ALS2);
    float* ald2  = (float*)(wsb + A_ALD2);
    int*   deg   = (int*)  (wsb + A_DEG);
    int*   offs  = (int*)  (wsb + A_OFFS);
    int*   cur   = (int*)  (wsb + A_CUR);
    int*   csrc  = (int*)  (wsb + A_CSRC);
    float* xc    = (float*)(wsb + A_XC);
    float* y1    = (float*)(wsb + A_Y1);
    int*   bsum  = (int*)  (wsb + A_BOFF);
    float* bpad  = (float*)(wsb + A_BPAD);
    u16*   wxt   = (u16*)  (wsb + A_WXT);
    float* fxp   = (float*)(wsb + A_FXP);
    __hip_bfloat16* w1hp = (__hip_bfloat16*)(wsb + A_W1HP);
    float* wsd   = (float*)(wsb + A_WSD);
    u16*   cwt   = (u16*)  (wsb + A_CWT);
    // aliases:
    float* hfin  = (float*)(wsb + A_HFIN);
    float* Amat2 = (float*)(wsb + A_AMAT);
    u16*   cvo   = (u16*)  (wsb + A_CVO);
    u16*   Mm    = (u16*)  (wsb + A_M);
    __hip_bfloat16* xpad = (__hip_bfloat16*)(wsb + A_XPAD);

    // prep
    k_prep<<<(PREP_TOTAL+255)/256, 256, 0, stream>>>(x, W1, W2, b1, fcxt_w, conv_w,
                                                     a_src1, a_dst1,
                                                     xpad, w1hp, w2tf, bpad, wxt, wsd, cwt, deg);
    // CSR build: count -> 3-kernel multi-block scan -> fill -> deterministic sort
    k_count  <<<(N_EDGES+255)/256, 256, 0, stream>>>(ei, deg);
    k_scan1  <<<NSCANB, 256, 0, stream>>>(deg, offs, bsum, N_NODES);
    k_scan2  <<<1, 256, 0, stream>>>(bsum, NSCANB);
    k_scan3  <<<NSCANB, 256, 0, stream>>>(bsum, offs, cur, N_NODES, NSCANB);
    k_fill   <<<(N_EDGES+N_NODES+255)/256, 256, 0, stream>>>(ei, cur, csrc);
    k_sortcsr<<<(N_NODES+255)/256, 256, 0, stream>>>(offs, csrc);

    // GAT layer 1 in x-space (no h materialization)
    k_att1x<<<(N_NODES*H1c+255)/256, 256, 0, stream>>>(x, wsd, als1, ald1);
    k_agg1x<<<N_NODES, 64, 0, stream>>>((const unsigned*)xpad, als1, ald1, offs, csrc,
                                        (unsigned*)xagg);

    // FUSED v5: 16-row blocks, serial per-head loads
    k_fuse12<<<(N_NODES+15)/16, 256, 0, stream>>>((const short*)xagg, (const short*)w1hp,
                                                  bpad, (const short*)w2tf,
                                                  a_src2, a_dst2, h2, als2, ald2);
    // ---- xagg dead; alias region (hfin/Amat2/cvo/Mm) usable ----

    // one-hot matrix build (alias region; must follow fuse12 which reads xagg)
    k_buildM<<<BGRAPHS, 256, 0, stream>>>(target, Mm);

    k_agg2<<<N_NODES, 64, 0, stream>>>(h2, als2, ald2, offs, csrc, b2, hfin);

    // pool + fc_g1 -> xc[:, 0:128]
    k_poolfcg<<<BGRAPHS, 128, 0, stream>>>(hfin, batch, fcg_w, fcg_b, xc);

    // conv path: Amat = M @ conv_w^T (hi+lo), then conv + fc_xt partials
    k_amat_mfma<<<dim3(MROWS/128, 2), 256, 0, stream>>>((const short*)Mm, (const short*)cwt,
                                                        Amat2);
    k_conv  <<<dim3(BGRAPHS, 8), 128, 0, stream>>>(Amat2, emb, conv_b, cvo);
    k_fcxt_mfma<<<dim3(BGRAPHS/64, 11), 256, 0, stream>>>((const short*)cvo, (const short*)wxt, fxp);

    // head MLP (W-reuse batched: fc1 8 graphs/block, fc2out 2 graphs/block)
    k_fc1<<<dim3(BGRAPHS/8, 4), 256, 0, stream>>>(xc, fxp, fcxt_b, fc1_w, fc1_b, y1);
    k_fc2out<<<BGRAPHS/2, 256, 0, stream>>>(y1, fc2_w, fc2_b, out_w, out_b, (float*)d_out);
}

// Round 18
// 494.015 us; speedup vs baseline: 1.0380x; 1.0103x over previous
//
#include <hip/hip_runtime.h>
#include <hip/hip_bf16.h>

// Problem constants (from reference)
#define N_NODES 50000
#define N_EDGES 200000
#define BGRAPHS 512
#define F0c 78
#define H1c 10
#define HC1 780     // H1*F0 (logical)
#define HSTR 832    // padded row stride: 10 head blocks of 80 (78 data + 2 pad) + 32 K-pad cols
#define C2c 128
#define SEQc 1000
#define VOCABc 26
#define NFc 32
#define KWc 8
#define LOUTc 121
#define EMBc 128
#define KX 96       // padded cols for xpad (78 -> 96)
#define KXT 3872    // NF*LOUT = 32*121 -> 121 MFMA k-steps
#define MROWS 13312 // 512*26 one-hot rows = 104 * 128 exactly
#define KM 1024     // padded K for Amat GEMM (1000 -> 1024)
#define W2TF_N (25*8*64*8)   // w2t in MFMA-fragment order: [kstep 25][colgrp 8][lane 64][8 bf16]
#define NSCANB 196  // scan blocks: ceil(50000/256)
#define XSTRB 1664  // padded xagg row stride in BYTES (13*128; swizzle row-closed)

typedef __attribute__((ext_vector_type(8))) short short8;
typedef __attribute__((ext_vector_type(4))) float f32x4;
typedef unsigned short u16;

static constexpr size_t alignup(size_t x) { return (x + 255) & ~size_t(255); }

// -------- workspace layout (bytes) --------
// A_HBUF region holds xagg bf16 [N][1664 B] (padded rows) = 83.2 MB exactly.
static constexpr size_t A_HBUF = 0;
static constexpr size_t A_OUT1 = alignup(A_HBUF + size_t(N_NODES)*HSTR*2);   // (dead slot; xpad alias lives here)
static constexpr size_t A_H2   = alignup(A_OUT1 + size_t(N_NODES)*HSTR*2);   // f32  [N,128]
static constexpr size_t A_W2T  = alignup(A_H2   + size_t(N_NODES)*C2c*4);    // bf16 w2tf fragment layout (200 KB)
static constexpr size_t A_ALS1 = alignup(A_W2T  + size_t(C2c)*HSTR*2);
static constexpr size_t A_ALD1 = alignup(A_ALS1 + size_t(N_NODES)*H1c*4);
static constexpr size_t A_ALS2 = alignup(A_ALD1 + size_t(N_NODES)*H1c*4);
static constexpr size_t A_ALD2 = alignup(A_ALS2 + size_t(N_NODES)*4);
static constexpr size_t A_DEG  = alignup(A_ALD2 + size_t(N_NODES)*4);
static constexpr size_t A_OFFS = alignup(A_DEG  + size_t(N_NODES)*4);
static constexpr size_t A_CUR  = alignup(A_OFFS + size_t(N_NODES+1)*4);
static constexpr size_t A_CSRC = alignup(A_CUR  + size_t(N_NODES)*4);
static constexpr size_t A_XC   = alignup(A_CSRC + size_t(N_EDGES+N_NODES)*4);
static constexpr size_t A_Y1   = alignup(A_XC   + size_t(BGRAPHS)*256*4);
static constexpr size_t A_BOFF = alignup(A_Y1   + size_t(BGRAPHS)*1024*4);   // scan block-sums live here
static constexpr size_t A_BPAD = alignup(A_BOFF + size_t(BGRAPHS)*(VOCABc+1)*4);
static constexpr size_t A_WXT  = alignup(A_BPAD + size_t(HSTR)*4);           // bf16 [121][8][64][8] fragment order
static constexpr size_t A_FXP  = alignup(A_WXT  + size_t(C2c)*KXT*2);        // f32 [11][512][128]
static constexpr size_t A_W1HP = alignup(A_FXP  + size_t(11)*BGRAPHS*C2c*4); // bf16 [10][80][96]
static constexpr size_t A_WSD  = alignup(A_W1HP + size_t(10)*80*96*2);       // f32 [2][10][78]
static constexpr size_t A_CWT  = alignup(A_WSD  + size_t(2)*H1c*F0c*4);      // bf16 [2][256][1024] hi/lo conv_w^T
static constexpr size_t A_END  = alignup(A_CWT  + size_t(2)*256*KM*2);
static_assert(W2TF_N*2 <= size_t(C2c)*HSTR*2, "w2tf fits old slot");
static_assert((NSCANB+1)*4 <= BGRAPHS*(VOCABc+1)*4, "bsum fits A_BOFF slot");
static_assert(size_t(N_NODES)*XSTRB <= size_t(N_NODES)*HSTR*2, "padded xagg fits");

// aliases inside xagg region (valid after k_fuse12 retires; xagg dead then):
static constexpr size_t A_HFIN = A_HBUF;                                        // f32 [N,128]
static constexpr size_t A_AMAT = alignup(A_HFIN + size_t(N_NODES)*C2c*4);       // f32 [13312][256]
static constexpr size_t A_CVO  = alignup(A_AMAT + size_t(MROWS)*256*4);         // bf16 [512][3872]
static constexpr size_t A_M    = alignup(A_CVO  + size_t(BGRAPHS)*KXT*2);       // bf16 [13312][1024] one-hot
static_assert(A_M + size_t(MROWS)*KM*2 <= size_t(N_NODES)*HSTR*2, "alias A overflow");
// alias inside out1 region (xpad dead before fuse12):
static constexpr size_t A_XPAD = A_OUT1;                                        // bf16 [N,96]
static_assert(size_t(N_NODES)*KX*2 <= size_t(N_NODES)*HSTR*2, "alias B overflow");

// -------- helpers --------
__device__ __forceinline__ float bflo(unsigned u) { return __uint_as_float(u << 16); }
__device__ __forceinline__ float bfhi(unsigned u) { return __uint_as_float(u & 0xffff0000u); }
__device__ __forceinline__ u16 f2bf(float v) {
    __hip_bfloat16 b = __float2bfloat16(v);
    return *(u16*)&b;
}

// async global->LDS, 16B per lane; LDS dest = wave-uniform base + lane*16
#define GLOAD16(g, l) __builtin_amdgcn_global_load_lds( \
    (const __attribute__((address_space(1))) void*)(g), \
    (__attribute__((address_space(3))) void*)(l), 16, 0, 0)

// ---------------- prep: deg init + conversions + folded attention vectors ----------------
__global__ void k_prep(const float* __restrict__ x, const float* __restrict__ W1,
                       const float* __restrict__ W2, const float* __restrict__ b1,
                       const float* __restrict__ fcxt_w, const float* __restrict__ conv_w,
                       const float* __restrict__ a_src1, const float* __restrict__ a_dst1,
                       __hip_bfloat16* __restrict__ xpad, __hip_bfloat16* __restrict__ w1hp,
                       u16* __restrict__ w2tf, float* __restrict__ bpad,
                       u16* __restrict__ wxt, float* __restrict__ wsd,
                       u16* __restrict__ cwt, int* __restrict__ deg) {
    int i = blockIdx.x*256 + threadIdx.x;
    const int R0 = N_NODES;
    const int R1 = R0 + N_NODES*KX;
    const int R2 = R1 + 10*80*96;
    const int R3 = R2 + W2TF_N;
    const int R4 = R3 + HSTR;
    const int R5 = R4 + C2c*KXT;
    const int R6 = R5 + 2*H1c*F0c;
    const int R7 = R6 + 256*KM;
    if (i < R0) {
        deg[i] = 1;   // self loop
    } else if (i < R1) {
        int t = i - R0; int n = t / KX, c = t - n*KX;
        xpad[t] = __float2bfloat16(c < F0c ? x[(size_t)n*F0c + c] : 0.f);
    } else if (i < R2) {
        int t = i - R1; int hh = t / 7680, rem = t - hh*7680;
        int j = rem / 96, k = rem - j*96;
        w1hp[t] = __float2bfloat16((j < F0c && k < F0c) ? W1[(size_t)k*HC1 + hh*F0c + j] : 0.f);
    } else if (i < R3) {
        // w2t in MFMA fragment order: frag index -> (kstep, colgrp, quad, m16), elem t in 0..7
        int t = i - R2; int frag = t >> 3, tt = t & 7;
        int m16 = frag & 15, quad = (frag >> 4) & 3, cbg = (frag >> 6) & 7, kstep = frag >> 9;
        int col = cbg*16 + m16;
        int k = kstep*32 + quad*8 + tt;
        int hh = k / 80, cc = k - hh*80;
        w2tf[t] = f2bf((cc < F0c) ? W2[(size_t)(hh*F0c + cc)*C2c + col] : 0.f);
    } else if (i < R4) {
        int p = i - R3; int hh = p / 80, cc = p - hh*80;
        bpad[p] = (hh < H1c && cc < F0c) ? b1[hh*F0c + cc] : 0.f;
    } else if (i < R5) {
        // fc_xt weights in MFMA fragment order: [kt 121][ct 8][lane 64][8 bf16]
        int t = i - R4; int frag = t >> 3, tt = t & 7;
        int lane = frag & 63, m16 = lane & 15, quad = lane >> 4;
        int ct = (frag >> 6) & 7, kt = frag >> 9;
        wxt[t] = f2bf(fcxt_w[(size_t)(kt*32 + quad*8 + tt)*C2c + (ct*16 + m16)]);
    } else if (i < R6) {
        int t = i - R5; int sd = t / (H1c*F0c), rem = t - sd*(H1c*F0c);
        int hh = rem / F0c, c = rem - hh*F0c;
        const float* a = sd ? a_dst1 : a_src1;
        float v = 0.f;
        for (int j = 0; j < F0c; j++) v += W1[(size_t)c*HC1 + hh*F0c + j] * a[hh*F0c + j];
        wsd[t] = v;
    } else if (i < R7) {
        // conv_w^T hi/lo split: cwt[0][col][i] = bf16(v), cwt[1][col][i] = bf16(v - f32(hi))
        int t = i - R6; int col = t >> 10, ii = t & (KM-1);
        int o = col >> 3, k = col & 7;
        float v = (ii < SEQc) ? conv_w[((size_t)o*SEQc + ii)*KWc + k] : 0.f;
        u16 h = f2bf(v);
        float hv = __uint_as_float((unsigned)h << 16);
        cwt[(size_t)col*KM + ii] = h;
        cwt[(size_t)256*KM + (size_t)col*KM + ii] = f2bf(v - hv);
    }
}
#define PREP_TOTAL (N_NODES + N_NODES*KX + 10*80*96 + W2TF_N + HSTR + C2c*KXT + 2*H1c*F0c + 256*KM)

// ---------------- CSR build ----------------
__global__ void k_count(const int* __restrict__ ei, int* deg) {
    int i = blockIdx.x*256 + threadIdx.x;
    if (i < N_EDGES) atomicAdd(&deg[ei[N_EDGES + i]], 1);
}
// Multi-block exclusive scan (R13: replaced single-block scan, -37us). Integer-exact.
__global__ void k_scan1(const int* __restrict__ deg, int* __restrict__ offs,
                        int* __restrict__ bsum, int n) {
    int b = blockIdx.x, tid = threadIdx.x, lane = tid & 63, wid = tid >> 6;
    int i = b*256 + tid;
    int v0 = (i < n) ? deg[i] : 0;
    int v = v0;
    for (int d = 1; d < 64; d <<= 1) { int t = __shfl_up(v, d, 64); if (lane >= d) v += t; }
    __shared__ int ws[4];
    if (lane == 63) ws[wid] = v;
    __syncthreads();
    if (tid == 0) {
        int r = 0;
        #pragma unroll
        for (int w = 0; w < 4; w++) { int t = ws[w]; ws[w] = r; r += t; }
        bsum[b] = r;
    }
    __syncthreads();
    if (i < n) offs[i] = ws[wid] + (v - v0);   // exclusive local prefix
}
__global__ void k_scan2(int* __restrict__ bsum, int nb) {
    __shared__ int s[NSCANB];
    int tid = threadIdx.x;
    for (int i = tid; i < nb; i += 256) s[i] = bsum[i];
    __syncthreads();
    if (tid == 0) {
        int r = 0;
        for (int b = 0; b < nb; b++) { int t = s[b]; s[b] = r; r += t; }
        bsum[nb] = r;                           // total
    }
    __syncthreads();
    for (int i = tid; i < nb; i += 256) bsum[i] = s[i];
}
__global__ void k_scan3(const int* __restrict__ bsum, int* __restrict__ offs,
                        int* __restrict__ cur, int n, int nb) {
    int b = blockIdx.x, i = b*256 + threadIdx.x;
    if (i < n) {
        int o = offs[i] + bsum[b];
        offs[i] = o; cur[i] = o;
    } else if (i == n) {
        offs[n] = bsum[nb];
    }
}
__global__ void k_fill(const int* __restrict__ ei, int* cur, int* __restrict__ csrc) {
    int i = blockIdx.x*256 + threadIdx.x;
    if (i < N_EDGES) {
        int s = ei[i], d = ei[N_EDGES + i];
        int p = atomicAdd(&cur[d], 1);
        csrc[p] = s;
    } else if (i < N_EDGES + N_NODES) {
        int n = i - N_EDGES;
        int p = atomicAdd(&cur[n], 1);
        csrc[p] = n;
    }
}
// determinize: sort each CSR segment (atomic fill order varies run-to-run)
__global__ void k_sortcsr(const int* __restrict__ offs, int* __restrict__ csrc) {
    int n = blockIdx.x*256 + threadIdx.x;
    if (n >= N_NODES) return;
    int s = offs[n], e = offs[n+1];
    for (int i = s + 1; i < e; i++) {
        int v = csrc[i];
        int j = i - 1;
        while (j >= s && csrc[j] > v) { csrc[j+1] = csrc[j]; j--; }
        csrc[j+1] = v;
    }
}

// ---------------- layer-1 attention logits, direct from x: als = x @ (W1_h a_h) ----------------
__global__ void k_att1x(const float* __restrict__ x, const float* __restrict__ wsd,
                        float* __restrict__ als, float* __restrict__ ald) {
    int i = blockIdx.x*256 + threadIdx.x;
    if (i >= N_NODES*H1c) return;
    int n = i / H1c, hh = i - n*H1c;
    const float* xr = x + (size_t)n*F0c;
    const float* ws = wsd + hh*F0c;
    const float* wd = wsd + H1c*F0c + hh*F0c;
    float s1 = 0.f, s2 = 0.f;
    for (int c = 0; c < F0c; c++) { float v = xr[c]; s1 += v*ws[c]; s2 += v*wd[c]; }
    als[i] = s1; ald[i] = s2;
}

// ---------------- layer-1 aggregation in x-space -> padded xagg rows (1664 B stride) ----------------
// FINAL structure (1-wave free-running blocks; R10/R14/R16 established latency-bound).
// R18 change: output row stride padded 1600 -> 1664 B (13*128) so fuse12 can bulk-stage
// rows with a row-closed XOR swizzle; 64 B pad zeroed (overread slots must be exact 0).
__global__ void k_agg1x(const unsigned* __restrict__ xpu, const float* __restrict__ als,
                        const float* __restrict__ ald, const int* __restrict__ offs,
                        const int* __restrict__ csrc, unsigned* __restrict__ xaggu) {
    constexpr int H = H1c;
    int dn = blockIdx.x, lane = threadIdx.x;   // 64
    int s = offs[dn], e = offs[dn+1], deg = e - s;
    __shared__ float wexp[64*H];               // 2560 B
    __shared__ int   ssrc[64];
    __shared__ float ms[H], dinv_s[H];
    const size_t rbase = (size_t)dn * (XSTRB/4);   // 416 uints per padded row

    if (lane < 16) xaggu[rbase + 400 + lane] = 0u; // zero 64 B pad (bytes 1600..1663)

    if (deg <= 64) {
        if (lane < deg) ssrc[lane] = csrc[s + lane];
        __syncthreads();
        for (int idx = lane; idx < deg*H; idx += 64) {
            int j = idx / H, hh = idx - j*H;
            float al = als[(size_t)ssrc[j]*H + hh] + ald[(size_t)dn*H + hh];
            wexp[idx] = (al >= 0.f) ? al : 0.2f*al;
        }
        __syncthreads();
        if (lane < H) {
            float m = -1e30f;
            for (int j = 0; j < deg; j++) m = fmaxf(m, wexp[j*H + lane]);
            float den = 0.f;
            for (int j = 0; j < deg; j++) den += __expf(wexp[j*H + lane] - m);
            ms[lane] = m; dinv_s[lane] = 1.f/(den + 1e-16f);
        }
        __syncthreads();
        for (int idx = lane; idx < deg*H; idx += 64) {
            int hh = idx % H;
            wexp[idx] = __expf(wexp[idx] - ms[hh]) * dinv_s[hh];
        }
        __syncthreads();
        if (lane < 40) {                       // uint c covers x cols 2c,2c+1 (cols 0..79)
            float accL[H], accH[H];
            #pragma unroll
            for (int hh = 0; hh < H; hh++) { accL[hh] = 0.f; accH[hh] = 0.f; }
            int j = 0;
            for (; j + 1 < deg; j += 2) {
                unsigned ua = xpu[(size_t)ssrc[j]*48 + lane];
                unsigned ub = xpu[(size_t)ssrc[j+1]*48 + lane];
                float a0 = bflo(ua), a1 = bfhi(ua), b0 = bflo(ub), b1 = bfhi(ub);
                #pragma unroll
                for (int hh = 0; hh < H; hh++) {
                    float wA = wexp[j*H + hh], wB = wexp[(j+1)*H + hh];
                    accL[hh] += wA*a0 + wB*b0;
                    accH[hh] += wA*a1 + wB*b1;
                }
            }
            if (j < deg) {
                unsigned ua = xpu[(size_t)ssrc[j]*48 + lane];
                float a0 = bflo(ua), a1 = bfhi(ua);
                #pragma unroll
                for (int hh = 0; hh < H; hh++) {
                    float wA = wexp[j*H + hh];
                    accL[hh] += wA*a0;
                    accH[hh] += wA*a1;
                }
            }
            #pragma unroll
            for (int hh = 0; hh < H; hh++) {
                unsigned p = (unsigned)f2bf(accL[hh]) | ((unsigned)f2bf(accH[hh]) << 16);
                xaggu[rbase + hh*40 + lane] = p;
            }
        }
    } else {
        // fallback deg>64 (practically never): recompute alpha inline, guaranteed correct
        if (lane < H) {
            float adv = ald[(size_t)dn*H + lane];
            float m = -1e30f;
            for (int j = s; j < e; j++) {
                float al = als[(size_t)csrc[j]*H + lane] + adv;
                al = (al >= 0.f) ? al : 0.2f*al;
                m = fmaxf(m, al);
            }
            float den = 0.f;
            for (int j = s; j < e; j++) {
                float al = als[(size_t)csrc[j]*H + lane] + adv;
                al = (al >= 0.f) ? al : 0.2f*al;
                den += __expf(al - m);
            }
            ms[lane] = m; dinv_s[lane] = 1.f/(den + 1e-16f);
        }
        __syncthreads();
        if (lane < 40) {
            float accL[H], accH[H];
            #pragma unroll
            for (int hh = 0; hh < H; hh++) { accL[hh] = 0.f; accH[hh] = 0.f; }
            for (int j = s; j < e; j++) {
                int sj = csrc[j];
                unsigned ua = xpu[(size_t)sj*48 + lane];
                float a0 = bflo(ua), a1 = bfhi(ua);
                #pragma unroll
                for (int hh = 0; hh < H; hh++) {
                    float al = als[(size_t)sj*H + hh] + ald[(size_t)dn*H + hh];
                    al = (al >= 0.f) ? al : 0.2f*al;
                    float a = __expf(al - ms[hh]) * dinv_s[hh];
                    accL[hh] += a*a0;
                    accH[hh] += a*a1;
                }
            }
            #pragma unroll
            for (int hh = 0; hh < H; hh++) {
                unsigned p = (unsigned)f2bf(accL[hh]) | ((unsigned)f2bf(accH[hh]) << 16);
                xaggu[rbase + hh*40 + lane] = p;
            }
        }
    }
}

// ---------------- FUSED v6: bulk-staged A tile + gemm1(ELU) + gemm2 + att2 fold ----------------
// R18 change vs v5: phase-1's ~27 serial per-head global loads per wave (64 B-granular,
// 1600 B stride -- the documented latency exposure) replaced by 7 coalesced global_load_lds
// issues staging the whole 16x1664 B xagg tile into Xs with inverse-swizzled source
// (LDS[row][cb] = xagg[row][cb ^ ((row&7)<<4)]). Phase-1 A-fragment reads use R16's
// correctness-validated Xs pattern (0 bank conflicts measured). Values bit-identical:
// same bf16 data, pad slots exact 0 (zeroed by agg1x) so kt=2/quad>=2 overreads stay 0.
// LDS 53,248 B -> 3 blocks/CU (matches the ~36% occupancy v5 already achieved).
__global__ void __launch_bounds__(256, 8)
k_fuse12(const short* __restrict__ xagg, const short* __restrict__ w1hp,
         const float* __restrict__ bpad, const short* __restrict__ w2tf,
         const float* __restrict__ a_src2, const float* __restrict__ a_dst2,
         float* __restrict__ Cout, float* __restrict__ als2, float* __restrict__ ald2) {
    __shared__ __attribute__((aligned(16))) short Xs[16*832];      // 26,624 B staged A tile
    __shared__ __attribute__((aligned(16))) short As[16*832];      // 26,624 B phase-1 out
    int tid = threadIdx.x;
    int wave = tid >> 6, lane = tid & 63;                          // 4 waves
    int m16 = lane & 15, quad = lane >> 4;
    int blockrow = blockIdx.x * 16;                                // 3125*16 = 50000 exact

    // ---- stage: 1664 x 16 B chunks; LDS dest wave-uniform base (+lane*16 by HW) ----
    #pragma unroll
    for (int it = 0; it < 7; it++) {
        int c = it*256 + wave*64 + lane;         // chunk id
        if (it < 6 || wave < 2) {                // 1664 = 6*256 + 2*64 (wave-uniform guard)
            int row = c / 104;                   // 104 chunks per 1664 B row
            int cb  = (c - row*104) << 4;
            size_t src = (size_t)(blockrow + row)*XSTRB + (cb ^ ((row & 7) << 4));
            GLOAD16((const char*)xagg + src, (char*)Xs + (size_t)(it*256 + wave*64)*16);
        }
    }
    __syncthreads();   // drains vmcnt: Xs complete

    // ---- phase 1: per-head 80x80 GEMM + bias + ELU, A from Xs -> As (swizzled bf16) ----
    {
        int hg = wave;                           // heads {hg, hg+4, hg+8 if hg<2}
        int S1 = (m16 & 7) << 4;
        const char* xrowR = (const char*)Xs + m16*XSTRB;
        for (int hh = hg; hh < H1c; hh += 4) {
            f32x4 acc1[5];
            #pragma unroll
            for (int ct = 0; ct < 5; ct++) acc1[ct] = (f32x4){0.f,0.f,0.f,0.f};
            #pragma unroll
            for (int kt = 0; kt < 3; kt++) {
                // kt=2,quad>=2 overreads hit zeroed pad bytes -> exact 0 x B-zero = 0
                short8 af = *(const short8*)(xrowR + ((hh*160 + (kt*4 + quad)*16) ^ S1));
                #pragma unroll
                for (int ct = 0; ct < 5; ct++) {
                    const short8* brow = (const short8*)(w1hp + (size_t)(hh*80 + ct*16 + m16)*96);
                    acc1[ct] = __builtin_amdgcn_mfma_f32_16x16x32_bf16(af, brow[kt*4 + quad],
                                                                      acc1[ct], 0, 0, 0);
                }
            }
            #pragma unroll
            for (int ct = 0; ct < 5; ct++) {
                int col = hh*80 + ct*16 + m16;
                float bv = bpad[col];
                #pragma unroll
                for (int r = 0; r < 4; r++) {
                    int rl = quad*4 + r;
                    float v = acc1[ct][r] + bv;
                    v = (v > 0.f) ? v : (__expf(v) - 1.f);
                    *(u16*)((char*)As + rl*1664 + ((col*2) ^ ((rl & 7) << 4))) = f2bf(v);
                }
            }
        }
    }
    __syncthreads();   // As complete (cols 800..831 never read: K-loop stops at 800)

    // ---- phase 2: gemm2, A from LDS, B direct from global fragment layout; no barriers ----
    int cg = wave;                               // 4 col-groups of 32
    f32x4 acc[2];
    acc[0] = (f32x4){0.f,0.f,0.f,0.f};
    acc[1] = (f32x4){0.f,0.f,0.f,0.f};
    int S = (m16 & 7) << 4;                      // read-side swizzle (row&7 == m16&7)
    const char* asRow = (const char*)As + (size_t)m16*1664;
    const short8* bp = (const short8*)w2tf;
    #pragma unroll 5
    for (int kstep = 0; kstep < 25; kstep++) {
        short8 af = *(const short8*)(asRow + ((kstep*64 + quad*16) ^ S));
        short8 b0 = bp[(size_t)(kstep*8 + cg*2    )*64 + lane];
        short8 b1 = bp[(size_t)(kstep*8 + cg*2 + 1)*64 + lane];
        acc[0] = __builtin_amdgcn_mfma_f32_16x16x32_bf16(af, b0, acc[0], 0, 0, 0);
        acc[1] = __builtin_amdgcn_mfma_f32_16x16x32_bf16(af, b1, acc[1], 0, 0, 0);
    }

    // ---- epilogue: C-write (global; does not touch As) ----
    float asv[2], adv[2];
    #pragma unroll
    for (int ct = 0; ct < 2; ct++) {
        asv[ct] = a_src2[cg*32 + ct*16 + m16];
        adv[ct] = a_dst2[cg*32 + ct*16 + m16];
    }
    #pragma unroll
    for (int ct = 0; ct < 2; ct++) {
        int col = cg*32 + ct*16 + m16;
        #pragma unroll
        for (int r = 0; r < 4; r++) {
            int orow = blockrow + quad*4 + r;
            Cout[(size_t)orow*C2c + col] = acc[ct][r];
        }
    }

    // ---- att2 fold: partials overlaid on As (dead after phase 2) ----
    __syncthreads();                             // all As reads complete before reuse
    float* sred  = (float*)As;                   // [16][4]
    float* sredd = sred + 64;                    // [16][4]
    #pragma unroll
    for (int r = 0; r < 4; r++) {
        float s1 = 0.f, s2 = 0.f;
        #pragma unroll
        for (int ct = 0; ct < 2; ct++) { s1 += acc[ct][r]*asv[ct]; s2 += acc[ct][r]*adv[ct]; }
        #pragma unroll
        for (int d = 1; d < 16; d <<= 1) { s1 += __shfl_xor(s1, d, 64); s2 += __shfl_xor(s2, d, 64); }
        if (m16 == 0) {
            int rl = quad*4 + r;
            sred[rl*4 + cg] = s1;
            sredd[rl*4 + cg] = s2;
        }
    }
    __syncthreads();
    if (tid < 16) {
        int orow = blockrow + tid;
        als2[orow] = sred[tid*4+0] + sred[tid*4+1] + sred[tid*4+2] + sred[tid*4+3];
        ald2[orow] = sredd[tid*4+0] + sredd[tid*4+1] + sredd[tid*4+2] + sredd[tid*4+3];
    }
}

// ---------------- GAT layer-2 aggregation (H=1, C=128 f32) ----------------
// FINAL (R13/R15 config): 1-wave blocks; gather latency-bound (R10/R14/R16 established).
__global__ void k_agg2(const float* __restrict__ h2, const float* __restrict__ als,
                       const float* __restrict__ ald, const int* __restrict__ offs,
                       const int* __restrict__ csrc, const float* __restrict__ b2,
                       float* __restrict__ out) {
    int dn = blockIdx.x, lane = threadIdx.x;   // 64
    int s = offs[dn], e = offs[dn+1], deg = e - s;
    __shared__ float wexp[128];
    __shared__ int ssrc[128];

    if (deg <= 128) {
        float adv = ald[dn];
        for (int j = lane; j < deg; j += 64) {
            int sj = csrc[s + j];
            ssrc[j] = sj;
            float al = als[sj] + adv;
            wexp[j] = (al >= 0.f) ? al : 0.2f*al;
        }
        __syncthreads();
        float m = -1e30f;
        for (int j = lane; j < deg; j += 64) m = fmaxf(m, wexp[j]);
        #pragma unroll
        for (int d = 32; d > 0; d >>= 1) m = fmaxf(m, __shfl_xor(m, d, 64));
        __syncthreads();
        float den = 0.f;
        for (int j = lane; j < deg; j += 64) {
            float ex = __expf(wexp[j] - m);
            wexp[j] = ex;
            den += ex;
        }
        #pragma unroll
        for (int d = 32; d > 0; d >>= 1) den += __shfl_xor(den, d, 64);
        float dinv = 1.f/(den + 1e-16f);
        __syncthreads();
        float2 acc = {0.f, 0.f};
        for (int j = 0; j < deg; j++) {
            float alpha = wexp[j] * dinv;
            float2 v = ((const float2*)(h2 + (size_t)ssrc[j]*C2c))[lane];
            acc.x += alpha*v.x; acc.y += alpha*v.y;
        }
        float2 o;
        o.x = fmaxf(acc.x + b2[2*lane], 0.f);
        o.y = fmaxf(acc.y + b2[2*lane+1], 0.f);
        ((float2*)(out + (size_t)dn*C2c))[lane] = o;
    } else {
        __shared__ float sm[2];
        if (lane == 0) {
            float adv = ald[dn];
            float m = -1e30f;
            for (int j = s; j < e; j++) {
                float al = als[csrc[j]] + adv;
                al = (al >= 0.f) ? al : 0.2f*al;
                m = fmaxf(m, al);
            }
            float den = 0.f;
            for (int j = s; j < e; j++) {
                float al = als[csrc[j]] + adv;
                al = (al >= 0.f) ? al : 0.2f*al;
                den += __expf(al - m);
            }
            sm[0] = m; sm[1] = 1.f/(den + 1e-16f);
        }
        __syncthreads();
        float m = sm[0], dinv = sm[1], adv = ald[dn];
        float2 acc = {0.f, 0.f};
        for (int j = s; j < e; j++) {
            int sj = csrc[j];
            float al = als[sj] + adv;
            al = (al >= 0.f) ? al : 0.2f*al;
            float alpha = __expf(al - m) * dinv;
            float2 v = ((const float2*)(h2 + (size_t)sj*C2c))[lane];
            acc.x += alpha*v.x; acc.y += alpha*v.y;
        }
        float2 o;
        o.x = fmaxf(acc.x + b2[2*lane], 0.f);
        o.y = fmaxf(acc.y + b2[2*lane+1], 0.f);
        ((float2*)(out + (size_t)dn*C2c))[lane] = o;
    }
}

// ---------------- pool + fc_g1 merged (g stays in LDS) ----------------
__global__ void k_poolfcg(const float* __restrict__ hf, const int* __restrict__ batch,
                          const float* __restrict__ W, const float* __restrict__ bias,
                          float* __restrict__ xc) {
    int b = blockIdx.x, tid = threadIdx.x;    // 128
    __shared__ int se[2];
    __shared__ float gs[C2c];
    if (tid < 2) {
        int key = b + tid;
        int lo = 0, hi = N_NODES;
        while (lo < hi) { int mid = (lo+hi) >> 1; if (batch[mid] < key) lo = mid+1; else hi = mid; }
        se[tid] = lo;
    }
    __syncthreads();
    int s = se[0], e = se[1];
    float m = -1e30f;
    for (int n = s; n < e; n++) m = fmaxf(m, hf[(size_t)n*C2c + tid]);
    gs[tid] = m;
    __syncthreads();
    float acc = bias[tid];
    for (int k = 0; k < C2c; k++) acc += gs[k] * W[k*C2c + tid];
    xc[b*256 + tid] = fmaxf(acc, 0.f);
}

// ---------------- conv path ----------------
// build one-hot matrix M[(b*26+t)][i] = (target[b,i]==t), bf16, K padded to 1024.
__global__ void k_buildM(const int* __restrict__ target, u16* __restrict__ Mm) {
    int b = blockIdx.x, tid = threadIdx.x;    // 256
    short8 z = (short8){0,0,0,0,0,0,0,0};
    short8* base = (short8*)(Mm + (size_t)b*VOCABc*KM);
    for (int i = tid; i < VOCABc*KM/8; i += 256) base[i] = z;
    __syncthreads();
    for (int i = tid; i < SEQc; i += 256) {
        int t = target[(size_t)b*SEQc + i];
        Mm[((size_t)b*VOCABc + t)*KM + i] = (u16)0x3F80;   // bf16 1.0
    }
}

// Amat via MFMA: A2[13312][256] = M[13312][1024] @ cwt^T (hi) + M @ cwt^T (lo).
__global__ void __launch_bounds__(256, 1)
k_amat_mfma(const short* __restrict__ Mm, const short* __restrict__ cwt,
            float* __restrict__ A2) {
    __shared__ __attribute__((aligned(16))) short As[2][128*64];
    __shared__ __attribute__((aligned(16))) short Bh[2][128*64];
    __shared__ __attribute__((aligned(16))) short Bl[2][128*64];
    int tid = threadIdx.x;
    int wave = tid >> 6, lane = tid & 63;
    int m16 = lane & 15, quad = lane >> 4;
    int blockrow = blockIdx.x * 128;       // 104 row-tiles
    int colbase  = blockIdx.y * 128;       // 2 col-tiles

    size_t aoff[4], bo[4];
    #pragma unroll
    for (int i = 0; i < 4; i++) {
        int c = wave*256 + i*64 + lane;
        int row = c >> 3;
        int cb  = (c & 7) << 4;
        int srcb = cb ^ ((row & 7) << 4);
        aoff[i] = (size_t)(blockrow + row) * (KM*2) + srcb;
        bo[i]   = (size_t)(colbase  + row) * (KM*2) + srcb;
    }
    const char* hbase = (const char*)cwt;
    const char* lbase = (const char*)(cwt + (size_t)256*KM);

    f32x4 acc[2][8];
    #pragma unroll
    for (int wr = 0; wr < 2; wr++)
        #pragma unroll
        for (int ct = 0; ct < 8; ct++) acc[wr][ct] = (f32x4){0.f,0.f,0.f,0.f};

    #pragma unroll
    for (int i = 0; i < 4; i++) {
        GLOAD16((const char*)Mm + aoff[i], &As[0][(wave*256 + i*64)*8]);
        GLOAD16(hbase + bo[i],             &Bh[0][(wave*256 + i*64)*8]);
        GLOAD16(lbase + bo[i],             &Bl[0][(wave*256 + i*64)*8]);
    }
    __syncthreads();

    int cur = 0;
    int S = (m16 & 7) << 4;
    for (int s = 0; s < KM/64; s++) {
        if (s + 1 < KM/64) {
            size_t kb = (size_t)(s + 1) * 128;
            #pragma unroll
            for (int i = 0; i < 4; i++) {
                GLOAD16((const char*)Mm + aoff[i] + kb, &As[cur^1][(wave*256 + i*64)*8]);
                GLOAD16(hbase + bo[i] + kb,             &Bh[cur^1][(wave*256 + i*64)*8]);
                GLOAD16(lbase + bo[i] + kb,             &Bl[cur^1][(wave*256 + i*64)*8]);
            }
        }
        const char* asBase = (const char*)&As[cur][0];
        const char* bhBase = (const char*)&Bh[cur][0];
        const char* blBase = (const char*)&Bl[cur][0];
        #pragma unroll
        for (int kk = 0; kk < 2; kk++) {
            int kb2 = (kk*64 + quad*16) ^ S;
            short8 af[2];
            #pragma unroll
            for (int wr = 0; wr < 2; wr++) {
                int row = wave*32 + wr*16 + m16;
                af[wr] = *(const short8*)(asBase + row*128 + kb2);
            }
            #pragma unroll
            for (int ct = 0; ct < 8; ct++) {
                int col = ct*16 + m16;
                short8 bhv = *(const short8*)(bhBase + col*128 + kb2);
                short8 blv = *(const short8*)(blBase + col*128 + kb2);
                acc[0][ct] = __builtin_amdgcn_mfma_f32_16x16x32_bf16(af[0], bhv, acc[0][ct], 0, 0, 0);
                acc[1][ct] = __builtin_amdgcn_mfma_f32_16x16x32_bf16(af[1], bhv, acc[1][ct], 0, 0, 0);
                acc[0][ct] = __builtin_amdgcn_mfma_f32_16x16x32_bf16(af[0], blv, acc[0][ct], 0, 0, 0);
                acc[1][ct] = __builtin_amdgcn_mfma_f32_16x16x32_bf16(af[1], blv, acc[1][ct], 0, 0, 0);
            }
        }
        __syncthreads();
        cur ^= 1;
    }

    #pragma unroll
    for (int wr = 0; wr < 2; wr++) {
        int rowbase = blockrow + wave*32 + wr*16 + quad*4;
        #pragma unroll
        for (int ct = 0; ct < 8; ct++) {
            int col = colbase + ct*16 + m16;
            #pragma unroll
            for (int r = 0; r < 4; r++) {
                A2[(size_t)(rowbase + r)*256 + col] = acc[wr][ct][r];
            }
        }
    }
}

__global__ void __launch_bounds__(128, 4)
k_conv(const float* __restrict__ A2, const float* __restrict__ emb,
       const float* __restrict__ convb, u16* __restrict__ convout) {
    int b = blockIdx.x, og = blockIdx.y;      // og in 0..7 -> o base og*4
    int tid = threadIdx.x;                    // 128
    __shared__ float embs[VOCABc*EMBc];       // 13.3 KB
    __shared__ float arow[4*VOCABc*KWc];      // 3.3 KB
    for (int i = tid; i < VOCABc*EMBc; i += 128) embs[i] = emb[i];
    for (int i = tid; i < 4*VOCABc*KWc; i += 128) {
        int o2 = i / (VOCABc*KWc);
        int rem = i - o2*(VOCABc*KWc);        // t*8+k
        int t = rem >> 3, k = rem & 7;
        arow[i] = A2[((size_t)b*VOCABc + t)*256 + (og*4 + o2)*8 + k];
    }
    __syncthreads();
    if (tid < LOUTc) {
        float a0 = convb[og*4+0], a1 = convb[og*4+1], a2 = convb[og*4+2], a3 = convb[og*4+3];
        for (int t = 0; t < VOCABc; t++) {
            #pragma unroll
            for (int k = 0; k < KWc; k++) {
                float ev = embs[t*EMBc + tid + k];
                a0 += arow[0*(VOCABc*KWc) + t*KWc + k] * ev;
                a1 += arow[1*(VOCABc*KWc) + t*KWc + k] * ev;
                a2 += arow[2*(VOCABc*KWc) + t*KWc + k] * ev;
                a3 += arow[3*(VOCABc*KWc) + t*KWc + k] * ev;
            }
        }
        size_t base = (size_t)b*KXT + (og*4)*LOUTc + tid;
        convout[base            ] = f2bf(fmaxf(a0, 0.f));
        convout[base +   LOUTc  ] = f2bf(fmaxf(a1, 0.f));
        convout[base + 2*LOUTc  ] = f2bf(fmaxf(a2, 0.f));
        convout[base + 3*LOUTc  ] = f2bf(fmaxf(a3, 0.f));
    }
}
// fc_xt partials via MFMA; B (wxt) in fragment order -> fully coalesced 16B/lane loads.
__global__ void k_fcxt_mfma(const short* __restrict__ cvo, const short* __restrict__ wxt,
                            float* __restrict__ fxp) {
    int wave = threadIdx.x >> 6, lane = threadIdx.x & 63;
    int m16 = lane & 15, quad = lane >> 4;
    int r0 = blockIdx.x*64 + wave*16;      // 512 rows = 8 blocks * 64
    int kt0 = blockIdx.y*11;               // 121 k-steps = 11 chunks * 11
    const short8* arow = (const short8*)(cvo + (size_t)(r0 + m16)*KXT);
    const short8* bp = (const short8*)wxt;
    f32x4 acc[8];
    #pragma unroll
    for (int ct = 0; ct < 8; ct++) acc[ct] = (f32x4){0.f,0.f,0.f,0.f};
    for (int kt = kt0; kt < kt0 + 11; kt++) {
        short8 af = arow[kt*4 + quad];
        #pragma unroll
        for (int ct = 0; ct < 8; ct++) {
            short8 bf = bp[(size_t)(kt*8 + ct)*64 + lane];
            acc[ct] = __builtin_amdgcn_mfma_f32_16x16x32_bf16(af, bf, acc[ct], 0, 0, 0);
        }
    }
    #pragma unroll
    for (int ct = 0; ct < 8; ct++) {
        int col = ct*16 + m16;
        #pragma unroll
        for (int r = 0; r < 4; r++) {
            int row = r0 + quad*4 + r;
            fxp[((size_t)blockIdx.y*BGRAPHS + row)*C2c + col] = acc[ct][r];
        }
    }
}

// ---------------- head MLP ----------------
// fc1 v2: 8 graphs per block x 4 col-quarters. W traffic 512 MB -> 64 MB. Bit-identical y1.
__global__ void __launch_bounds__(256, 4)
k_fc1(const float* __restrict__ xc, const float* __restrict__ fxp,
      const float* __restrict__ fcxt_b, const float* __restrict__ W,
      const float* __restrict__ bias, float* __restrict__ y1) {
    int g0 = blockIdx.x * 8;                  // 64 graph-groups
    int colq = blockIdx.y;                    // 4 col-quarters
    int tid = threadIdx.x;                    // 256
    __shared__ float xs[8][256];              // 8 KB
    for (int idx = tid; idx < 8*256; idx += 256) {
        int g = idx >> 8, k = idx & 255;
        int b = g0 + g;
        float v;
        if (k < 128) {
            v = xc[b*256 + k];
        } else {
            int col = k - 128;
            float s = fcxt_b[col];
            #pragma unroll
            for (int q = 0; q < 11; q++) s += fxp[((size_t)q*BGRAPHS + b)*C2c + col];
            v = s;
        }
        xs[g][k] = v;
    }
    __syncthreads();
    int col = colq*256 + tid;
    float a[8];
    #pragma unroll
    for (int g = 0; g < 8; g++) a[g] = bias[col];
    for (int k = 0; k < 256; k++) {
        float w = W[(size_t)k*1024 + col];    // coalesced; xs[g][k] is LDS broadcast
        #pragma unroll
        for (int g = 0; g < 8; g++) a[g] += xs[g][k] * w;
    }
    #pragma unroll
    for (int g = 0; g < 8; g++)
        y1[(size_t)(g0+g)*1024 + col] = fmaxf(a[g], 0.f);
}
// fc2out v2: 2 graphs per block. Bit-identical out.
__global__ void __launch_bounds__(256, 4)
k_fc2out(const float* __restrict__ y1, const float* __restrict__ W,
         const float* __restrict__ bias, const float* __restrict__ ow,
         const float* __restrict__ ob, float* __restrict__ out) {
    int g0 = blockIdx.x * 2;                  // 256 graph-groups
    int tid = threadIdx.x;                    // 256
    int lane = tid & 63, wid = tid >> 6;
    __shared__ float ys[2][1024];             // 8 KB
    __shared__ float wsum[2][4];
    for (int i = tid; i < 2048; i += 256)
        ys[i >> 10][i & 1023] = y1[(size_t)(g0 + (i >> 10))*1024 + (i & 1023)];
    __syncthreads();
    float acc0 = bias[tid], acc1 = bias[tid];
    for (int k = 0; k < 1024; k++) {
        float w = W[(size_t)k*256 + tid];     // coalesced; ys[g][k] is LDS broadcast
        acc0 += ys[0][k] * w;
        acc1 += ys[1][k] * w;
    }
    float v0 = fmaxf(acc0, 0.f) * ow[tid];
    float v1 = fmaxf(acc1, 0.f) * ow[tid];
    #pragma unroll
    for (int d = 32; d > 0; d >>= 1) { v0 += __shfl_xor(v0, d, 64); v1 += __shfl_xor(v1, d, 64); }
    if (lane == 0) { wsum[0][wid] = v0; wsum[1][wid] = v1; }
    __syncthreads();
    if (tid < 2)
        out[g0 + tid] = wsum[tid][0] + wsum[tid][1] + wsum[tid][2] + wsum[tid][3] + ob[0];
}

extern "C" void kernel_launch(void* const* d_in, const int* in_sizes, int n_in,
                              void* d_out, int out_size, void* d_ws, size_t ws_size,
                              hipStream_t stream) {
    (void)in_sizes; (void)n_in; (void)out_size;
    if (ws_size < A_END) return;   // guard: clean numeric-fail if ws too small

    const float* x       = (const float*)d_in[0];
    const int*   ei      = (const int*)  d_in[1];
    const int*   batch   = (const int*)  d_in[2];
    const int*   target  = (const int*)  d_in[3];
    const float* W1      = (const float*)d_in[4];
    const float* a_src1  = (const float*)d_in[5];
    const float* a_dst1  = (const float*)d_in[6];
    const float* b1      = (const float*)d_in[7];
    const float* W2      = (const float*)d_in[8];
    const float* a_src2  = (const float*)d_in[9];
    const float* a_dst2  = (const float*)d_in[10];
    const float* b2      = (const float*)d_in[11];
    const float* fcg_w   = (const float*)d_in[12];
    const float* fcg_b   = (const float*)d_in[13];
    const float* emb     = (const float*)d_in[14];
    const float* conv_w  = (const float*)d_in[15];
    const float* conv_b  = (const float*)d_in[16];
    const float* fcxt_w  = (const float*)d_in[17];
    const float* fcxt_b  = (const float*)d_in[18];
    const float* fc1_w   = (const float*)d_in[19];
    const float* fc1_b   = (const float*)d_in[20];
    const float* fc2_w   = (const float*)d_in[21];
    const float* fc2_b   = (const float*)d_in[22];
    const float* out_w   = (const float*)d_in[23];
    const float* out_b   = (const float*)d_in[24];

    char* wsb = (char*)d_ws;
    u16*   xagg  = (u16*)  (wsb + A_HBUF);
    float* h2    = (float*)(wsb + A_H2);
    u16*   w2tf  = (u16*)  (wsb + A_W2T);
    float* als1  = (float*)(wsb + A_ALS1);
    float* ald1  = (float*)(wsb + A_ALD1);
    float* als2  = (float*)(wsb + A_ALS2);
    float* ald2  = (float*)(wsb + A_ALD2);
    int*   deg   = (int*)  (wsb + A_DEG);
    int*   offs  = (int*)  (wsb + A_OFFS);
    int*   cur   = (int*)  (wsb + A_CUR);
    int*   csrc  = (int*)  (wsb + A_CSRC);
    float* xc    = (float*)(wsb + A_XC);
    float* y1    = (float*)(wsb + A_Y1);
    int*   bsum  = (int*)  (wsb + A_BOFF);
    float* bpad  = (float*)(wsb + A_BPAD);
    u16*   wxt   = (u16*)  (wsb + A_WXT);
    float* fxp   = (float*)(wsb + A_FXP);
    __hip_bfloat16* w1hp = (__hip_bfloat16*)(wsb + A_W1HP);
    float* wsd   = (float*)(wsb + A_WSD);
    u16*   cwt   = (u16*)  (wsb + A_CWT);
    // aliases:
    float* hfin  = (float*)(wsb + A_HFIN);
    float* Amat2 = (float*)(wsb + A_AMAT);
    u16*   cvo   = (u16*)  (wsb + A_CVO);
    u16*   Mm    = (u16*)  (wsb + A_M);
    __hip_bfloat16* xpad = (__hip_bfloat16*)(wsb + A_XPAD);

    // prep
    k_prep<<<(PREP_TOTAL+255)/256, 256, 0, stream>>>(x, W1, W2, b1, fcxt_w, conv_w,
                                                     a_src1, a_dst1,
                                                     xpad, w1hp, w2tf, bpad, wxt, wsd, cwt, deg);
    // CSR build: count -> 3-kernel multi-block scan -> fill -> deterministic sort
    k_count  <<<(N_EDGES+255)/256, 256, 0, stream>>>(ei, deg);
    k_scan1  <<<NSCANB, 256, 0, stream>>>(deg, offs, bsum, N_NODES);
    k_scan2  <<<1, 256, 0, stream>>>(bsum, NSCANB);
    k_scan3  <<<NSCANB, 256, 0, stream>>>(bsum, offs, cur, N_NODES, NSCANB);
    k_fill   <<<(N_EDGES+N_NODES+255)/256, 256, 0, stream>>>(ei, cur, csrc);
    k_sortcsr<<<(N_NODES+255)/256, 256, 0, stream>>>(offs, csrc);

    // GAT layer 1 in x-space (no h materialization)
    k_att1x<<<(N_NODES*H1c+255)/256, 256, 0, stream>>>(x, wsd, als1, ald1);
    k_agg1x<<<N_NODES, 64, 0, stream>>>((const unsigned*)xpad, als1, ald1, offs, csrc,
                                        (unsigned*)xagg);

    // FUSED v6: bulk-staged A tile, 16-row blocks
    k_fuse12<<<(N_NODES+15)/16, 256, 0, stream>>>((const short*)xagg, (const short*)w1hp,
                                                  bpad, (const short*)w2tf,
                                                  a_src2, a_dst2, h2, als2, ald2);
    // ---- xagg dead; alias region (hfin/Amat2/cvo/Mm) usable ----

    // one-hot matrix build (alias region; must follow fuse12 which reads xagg)
    k_buildM<<<BGRAPHS, 256, 0, stream>>>(target, Mm);

    k_agg2<<<N_NODES, 64, 0, stream>>>(h2, als2, ald2, offs, csrc, b2, hfin);

    // pool + fc_g1 -> xc[:, 0:128]
    k_poolfcg<<<BGRAPHS, 128, 0, stream>>>(hfin, batch, fcg_w, fcg_b, xc);

    // conv path: Amat = M @ conv_w^T (hi+lo), then conv + fc_xt partials
    k_amat_mfma<<<dim3(MROWS/128, 2), 256, 0, stream>>>((const short*)Mm, (const short*)cwt,
                                                        Amat2);
    k_conv  <<<dim3(BGRAPHS, 8), 128, 0, stream>>>(Amat2, emb, conv_b, cvo);
    k_fcxt_mfma<<<dim3(BGRAPHS/64, 11), 256, 0, stream>>>((const short*)cvo, (const short*)wxt, fxp);

    // head MLP (W-reuse batched: fc1 8 graphs/block, fc2out 2 graphs/block)
    k_fc1<<<dim3(BGRAPHS/8, 4), 256, 0, stream>>>(xc, fxp, fcxt_b, fc1_w, fc1_b, y1);
    k_fc2out<<<BGRAPHS/2, 256, 0, stream>>>(y1, fc2_w, fc2_b, out_w, out_b, (float*)d_out);
}